// Round 1
// baseline (3706.428 us; speedup 1.0000x reference)
//
#include <hip/hip_runtime.h>

#define SEQ 12

typedef __attribute__((ext_vector_type(8))) short bf16x8;   // 8 bf16 bit patterns (4 VGPRs)
typedef __attribute__((ext_vector_type(4))) float f32x4;
typedef __attribute__((ext_vector_type(4))) unsigned short us4;

__device__ __forceinline__ unsigned short f2bf(float x) {
    unsigned u = __builtin_bit_cast(unsigned, x);
    u += 0x7fffu + ((u >> 16) & 1u);            // round-to-nearest-even
    return (unsigned short)(u >> 16);
}
__device__ __forceinline__ float bf2f(unsigned short h) {
    unsigned u = ((unsigned)h) << 16;
    return __builtin_bit_cast(float, u);
}
__device__ __forceinline__ float sigf(float x) { return 1.0f / (1.0f + __expf(-x)); }
__device__ __forceinline__ float tanhf_(float x) {
    x = fminf(fmaxf(x, -15.0f), 15.0f);
    float e = __expf(2.0f * x);
    return (e - 1.0f) / (e + 1.0f);
}

// ---------------- weight pack kernel ----------------
// d_ws layout (ushort): [0,65536)  PRE0  = bf16(W_ih_l0[:, :128])  fragment-ordered
//                       [65536,..) INIT  = bf16(W_init [:, :128])
//                       [131072,.) L0    = bf16(W_hh_l0)
//                       [196608,.) L1    = bf16([W_ih_l1 | W_hh_l1])  K=256
// fragment order: chunk = ((w*4+G)*KK + kk), within chunk: lane*8+j,
//   n = G*128 + w*16 + (lane&15),  k = kk*32 + (lane>>4)*8 + j
__global__ void pack_w(const float* __restrict__ Winit, const float* __restrict__ Wihl0,
                       const float* __restrict__ Whhl0, const float* __restrict__ Wihl1,
                       const float* __restrict__ Whhl1, unsigned short* __restrict__ pk) {
    int id = blockIdx.x * 256 + threadIdx.x;
    if (id >= 327680) return;
    float v;
    if (id < 131072) {                       // PRE0 / INIT (stride 129, KK=4)
        int e = id & 65535;
        int c = e >> 9, r = e & 511;
        int lane = r >> 3, j = r & 7;
        int kk = c & 3, G = (c >> 2) & 3, w = c >> 4;
        int n = G * 128 + w * 16 + (lane & 15);
        int k = kk * 32 + (lane >> 4) * 8 + j;
        const float* W = (id >> 16) ? Winit : Wihl0;
        v = W[n * 129 + k];
    } else if (id < 196608) {                // L0 (stride 128, KK=4)
        int e = id - 131072;
        int c = e >> 9, r = e & 511;
        int lane = r >> 3, j = r & 7;
        int kk = c & 3, G = (c >> 2) & 3, w = c >> 4;
        int n = G * 128 + w * 16 + (lane & 15);
        int k = kk * 32 + (lane >> 4) * 8 + j;
        v = Whhl0[n * 128 + k];
    } else {                                 // L1 (K=256, KK=8)
        int e = id - 196608;
        int c = e >> 9, r = e & 511;
        int lane = r >> 3, j = r & 7;
        int kk = c & 7, G = (c >> 3) & 3, w = c >> 5;
        int n = G * 128 + w * 16 + (lane & 15);
        int k = kk * 32 + (lane >> 4) * 8 + j;
        v = (k < 128) ? Wihl1[n * 128 + k] : Whhl1[n * 128 + (k - 128)];
    }
    pk[id] = f2bf(v);
}

// ---------------- fused decoder kernel ----------------
// block: 512 thr (8 waves), Mt=64 samples. wave w owns hidden cols [16w,16w+16)
// across all 4 gates -> LSTM pointwise is lane-local in MFMA C-layout.
// h1/h2: bf16 in LDS, rows 128 bf16 (256B), XOR chunk swizzle (c ^ (m&15)) -> <=2-way banks.
__global__ __launch_bounds__(512, 2)
void traj_main(const float* __restrict__ fused, const float* __restrict__ intent,
               const float* __restrict__ Winit, const float* __restrict__ binit,
               const float* __restrict__ Wihl0, const float* __restrict__ bihl0,
               const float* __restrict__ bhhl0, const float* __restrict__ bihl1,
               const float* __restrict__ bhhl1, const float* __restrict__ Wout,
               const float* __restrict__ bout, const unsigned short* __restrict__ pk,
               float* __restrict__ out, int Bsz) {
    __shared__ __align__(16) unsigned short s_h1[64 * 128];
    __shared__ __align__(16) unsigned short s_h2[64 * 128];
    __shared__ __align__(16) unsigned short s_ct[2 * 64 * 128];   // c-init staging (bf16)

    const int tid = threadIdx.x;
    const int lane = tid & 63;
    const int w = tid >> 6;          // wave 0..7
    const int nq = lane & 15;
    const int quad = lane >> 4;
    const int m0 = blockIdx.x * 64;
    const int Bh = Bsz >> 1;

    const unsigned short* pkPRE = pk;
    const unsigned short* pkINI = pk + 65536;
    const unsigned short* pkL0  = pk + 131072;
    const unsigned short* pkL1  = pk + 196608;

    // per-lane column constants (n = G*128 + 16w + nq)
    float bpre[4], bl1[4], wcp[4], wci[4], bini[4];
#pragma unroll
    for (int G = 0; G < 4; ++G) {
        int n = G * 128 + w * 16 + nq;
        bpre[G] = bihl0[n] + bhhl0[n];
        bl1[G]  = bihl1[n] + bhhl1[n];
        wcp[G]  = Wihl0[n * 129 + 128];    // intent column
        wci[G]  = Winit[n * 129 + 128];
        bini[G] = binit[n];
    }

    // ---- stage x tile as bf16 (swizzled): rows 0..63 own samples -> s_h1,
    //      rows 64..95 init rows m0/2.., rows 96..127 init rows B/2+m0/2.. -> s_h2
#pragma unroll
    for (int it = 0; it < 8; ++it) {
        int f = it * 512 + tid;
        int row = f >> 5, fc = f & 31;
        int g = (row < 64) ? (m0 + row)
                           : ((row < 96) ? ((m0 >> 1) + (row - 64))
                                         : (Bh + (m0 >> 1) + (row - 96)));
        f32x4 v = *(const f32x4*)(fused + g * 128 + fc * 4);
        us4 u;
#pragma unroll
        for (int j = 0; j < 4; ++j) u[j] = f2bf(v[j]);
        int m = row & 63;
        int cp = (fc >> 1) ^ (m & 15);
        unsigned short* buf = (row < 64) ? s_h1 : s_h2;
        *(us4*)&buf[m * 128 + cp * 8 + (fc & 1) * 4] = u;
    }
    __syncthreads();

    // ---- phase A: pre0 = x@Wihl0^T (+b,+intent), initacc = x'@Winit^T (+b,+intent)
    f32x4 pre0[4][4], acc2[4][4];
#pragma unroll
    for (int mt = 0; mt < 4; ++mt)
#pragma unroll
        for (int G = 0; G < 4; ++G) {
            pre0[mt][G] = (f32x4){0.f, 0.f, 0.f, 0.f};
            acc2[mt][G] = (f32x4){0.f, 0.f, 0.f, 0.f};
        }
#pragma unroll
    for (int kk = 0; kk < 4; ++kk) {
        bf16x8 a[4], b[4], a2[4], b2[4];
#pragma unroll
        for (int mt = 0; mt < 4; ++mt) {
            int idx = (mt * 16 + nq) * 128 + (((kk * 4 + quad) ^ nq) << 3);
            a[mt]  = *(const bf16x8*)&s_h1[idx];
            a2[mt] = *(const bf16x8*)&s_h2[idx];
        }
#pragma unroll
        for (int G = 0; G < 4; ++G) {
            int off = ((w * 4 + G) * 4 + kk) * 512 + lane * 8;
            b[G]  = *(const bf16x8*)&pkPRE[off];
            b2[G] = *(const bf16x8*)&pkINI[off];
        }
#pragma unroll
        for (int mt = 0; mt < 4; ++mt)
#pragma unroll
            for (int G = 0; G < 4; ++G) {
                pre0[mt][G] = __builtin_amdgcn_mfma_f32_16x16x32_bf16(a[mt],  b[G],  pre0[mt][G], 0, 0, 0);
                acc2[mt][G] = __builtin_amdgcn_mfma_f32_16x16x32_bf16(a2[mt], b2[G], acc2[mt][G], 0, 0, 0);
            }
    }
#pragma unroll
    for (int mt = 0; mt < 4; ++mt)
#pragma unroll
        for (int r = 0; r < 4; ++r) {
            int ml = mt * 16 + quad * 4 + r;
            float iv = intent[m0 + ml];
            int grow = (mt < 2) ? ((m0 >> 1) + ml) : (Bh + (m0 >> 1) + (ml - 32));
            float iv2 = intent[grow];
#pragma unroll
            for (int G = 0; G < 4; ++G) {
                pre0[mt][G][r] += bpre[G] + iv * wcp[G];
                acc2[mt][G][r] += bini[G] + iv2 * wci[G];
            }
        }
    __syncthreads();   // x-tile reads complete

    // ---- unpack init (torch-faithful flat reshape):
    // init row r=(m>>1): G0=[0:128)->h even, G1->h odd, G2->c even, G3->c odd;
    // mt 0,1 -> layer0, mt 2,3 -> layer1
    {
        int kq = w * 16 + nq, kc = kq >> 3, klo = kq & 7;
#pragma unroll
        for (int mt = 0; mt < 4; ++mt)
#pragma unroll
            for (int r = 0; r < 4; ++r) {
                int ri = mt * 16 + quad * 4 + r;
                int layer = mt >> 1;
                int ril = ri & 31;
#pragma unroll
                for (int G = 0; G < 4; ++G) {
                    int ml = 2 * ril + (G & 1);
                    unsigned short hv = f2bf(acc2[mt][G][r]);
                    if (G < 2) {
                        unsigned short* hb = layer ? s_h2 : s_h1;
                        hb[ml * 128 + ((kc ^ (ml & 15)) << 3) + klo] = hv;
                    } else {
                        s_ct[(layer * 64 + ml) * 128 + kq] = hv;
                    }
                }
            }
    }
    __syncthreads();

    // ---- load c into C-layout registers
    f32x4 c1v[4], c2v[4];
    {
        int kq = w * 16 + nq;
#pragma unroll
        for (int mt = 0; mt < 4; ++mt)
#pragma unroll
            for (int r = 0; r < 4; ++r) {
                int ml = mt * 16 + quad * 4 + r;
                c1v[mt][r] = bf2f(s_ct[ml * 128 + kq]);
                c2v[mt][r] = bf2f(s_ct[(64 + ml) * 128 + kq]);
            }
    }

    // ---- 12 decode steps, state resident
    for (int s = 0; s < SEQ; ++s) {
        f32x4 acc[4][4];
        // layer0: g = pre0 + h1 @ Whhl0^T
#pragma unroll
        for (int mt = 0; mt < 4; ++mt)
#pragma unroll
            for (int G = 0; G < 4; ++G) acc[mt][G] = pre0[mt][G];
#pragma unroll
        for (int kk = 0; kk < 4; ++kk) {
            bf16x8 a[4], b[4];
#pragma unroll
            for (int mt = 0; mt < 4; ++mt)
                a[mt] = *(const bf16x8*)&s_h1[(mt * 16 + nq) * 128 + (((kk * 4 + quad) ^ nq) << 3)];
#pragma unroll
            for (int G = 0; G < 4; ++G)
                b[G] = *(const bf16x8*)&pkL0[((w * 4 + G) * 4 + kk) * 512 + lane * 8];
#pragma unroll
            for (int mt = 0; mt < 4; ++mt)
#pragma unroll
                for (int G = 0; G < 4; ++G)
                    acc[mt][G] = __builtin_amdgcn_mfma_f32_16x16x32_bf16(a[mt], b[G], acc[mt][G], 0, 0, 0);
        }
        __syncthreads();   // B1: h1 reads done
#pragma unroll
        for (int mt = 0; mt < 4; ++mt)
#pragma unroll
            for (int r = 0; r < 4; ++r) {
                float iv = acc[mt][0][r], fv = acc[mt][1][r], gv = acc[mt][2][r], ov = acc[mt][3][r];
                float c = c1v[mt][r];
                float cn = sigf(fv) * c + sigf(iv) * tanhf_(gv);
                float hn = sigf(ov) * tanhf_(cn);
                c1v[mt][r] = cn;
                int ml = mt * 16 + quad * 4 + r;
                s_h1[ml * 128 + ((((w * 2) + (nq >> 3)) ^ (quad * 4 + r)) << 3) + (nq & 7)] = f2bf(hn);
            }
        __syncthreads();   // B2: new h1 visible
        // layer1: g = b1 + [h1_new | h2] @ [Wihl1 | Whhl1]^T   (K=256)
#pragma unroll
        for (int mt = 0; mt < 4; ++mt)
#pragma unroll
            for (int G = 0; G < 4; ++G)
                acc[mt][G] = (f32x4){bl1[G], bl1[G], bl1[G], bl1[G]};
#pragma unroll
        for (int kk = 0; kk < 8; ++kk) {
            const unsigned short* hb = (kk < 4) ? s_h1 : s_h2;
            int kkl = kk & 3;
            bf16x8 a[4], b[4];
#pragma unroll
            for (int mt = 0; mt < 4; ++mt)
                a[mt] = *(const bf16x8*)&hb[(mt * 16 + nq) * 128 + (((kkl * 4 + quad) ^ nq) << 3)];
#pragma unroll
            for (int G = 0; G < 4; ++G)
                b[G] = *(const bf16x8*)&pkL1[((w * 4 + G) * 8 + kk) * 512 + lane * 8];
#pragma unroll
            for (int mt = 0; mt < 4; ++mt)
#pragma unroll
                for (int G = 0; G < 4; ++G)
                    acc[mt][G] = __builtin_amdgcn_mfma_f32_16x16x32_bf16(a[mt], b[G], acc[mt][G], 0, 0, 0);
        }
        __syncthreads();   // B3: h2 reads done
#pragma unroll
        for (int mt = 0; mt < 4; ++mt)
#pragma unroll
            for (int r = 0; r < 4; ++r) {
                float iv = acc[mt][0][r], fv = acc[mt][1][r], gv = acc[mt][2][r], ov = acc[mt][3][r];
                float c = c2v[mt][r];
                float cn = sigf(fv) * c + sigf(iv) * tanhf_(gv);
                float hn = sigf(ov) * tanhf_(cn);
                c2v[mt][r] = cn;
                int ml = mt * 16 + quad * 4 + r;
                s_h2[ml * 128 + ((((w * 2) + (nq >> 3)) ^ (quad * 4 + r)) << 3) + (nq & 7)] = f2bf(hn);
            }
        __syncthreads();   // B4: new h2 visible
        // output head (fp32): out[m, s, :] = h2_new @ Wout^T + bout
        if (tid < 128) {
            int ml = tid >> 1, oc = tid & 1;
            const float* wr = Wout + oc * 128;
            float s0 = 0.f, s1 = 0.f;
            int mx = ml & 15;
#pragma unroll
            for (int c = 0; c < 16; ++c) {
                int base = ml * 128 + ((c ^ mx) << 3);
                int k0 = c << 3;
#pragma unroll
                for (int j = 0; j < 8; j += 2) {
                    unsigned u = *(const unsigned*)&s_h2[base + j];
                    s0 += bf2f((unsigned short)u) * wr[k0 + j];
                    s1 += bf2f((unsigned short)(u >> 16)) * wr[k0 + j + 1];
                }
            }
            out[(m0 + ml) * 24 + s * 2 + oc] = s0 + s1 + bout[oc];
        }
    }
}

extern "C" void kernel_launch(void* const* d_in, const int* in_sizes, int n_in,
                              void* d_out, int out_size, void* d_ws, size_t ws_size,
                              hipStream_t stream) {
    const float* fused  = (const float*)d_in[0];
    const float* intent = (const float*)d_in[1];
    const float* Winit  = (const float*)d_in[2];
    const float* binit  = (const float*)d_in[3];
    const float* Wihl0  = (const float*)d_in[4];
    const float* Whhl0  = (const float*)d_in[5];
    const float* bihl0  = (const float*)d_in[6];
    const float* bhhl0  = (const float*)d_in[7];
    const float* Wihl1  = (const float*)d_in[8];
    const float* Whhl1  = (const float*)d_in[9];
    const float* bihl1  = (const float*)d_in[10];
    const float* bhhl1  = (const float*)d_in[11];
    const float* Wout   = (const float*)d_in[12];
    const float* bout   = (const float*)d_in[13];
    int Bsz = in_sizes[0] / 128;

    unsigned short* pkw = (unsigned short*)d_ws;   // 655,360 B used
    pack_w<<<1280, 256, 0, stream>>>(Winit, Wihl0, Whhl0, Wihl1, Whhl1, pkw);
    traj_main<<<Bsz / 64, 512, 0, stream>>>(fused, intent, Winit, binit, Wihl0, bihl0,
                                            bhhl0, bihl1, bhhl1, Wout, bout, pkw,
                                            (float*)d_out, Bsz);
}

// Round 2
// 3547.313 us; speedup vs baseline: 1.0449x; 1.0449x over previous
//
#include <hip/hip_runtime.h>

#define SEQ 12

typedef __attribute__((ext_vector_type(8))) short bf16x8;   // 8 bf16 bit patterns (4 VGPRs)
typedef __attribute__((ext_vector_type(4))) float f32x4;
typedef __attribute__((ext_vector_type(4))) unsigned short us4;

__device__ __forceinline__ unsigned short f2bf(float x) {
    unsigned u = __builtin_bit_cast(unsigned, x);
    u += 0x7fffu + ((u >> 16) & 1u);            // round-to-nearest-even
    return (unsigned short)(u >> 16);
}
__device__ __forceinline__ float bf2f(unsigned short h) {
    unsigned u = ((unsigned)h) << 16;
    return __builtin_bit_cast(float, u);
}
__device__ __forceinline__ float sigf(float x) { return 1.0f / (1.0f + __expf(-x)); }
__device__ __forceinline__ float tanhf_(float x) {
    x = fminf(fmaxf(x, -15.0f), 15.0f);
    float e = __expf(2.0f * x);
    return (e - 1.0f) / (e + 1.0f);
}

// ---------------- weight pack kernel ----------------
// d_ws layout (ushort), REPLICATED ncopy times at stride 327680 (640 KB/copy):
//   [0,65536)  PRE0  = bf16(W_ih_l0[:, :128])  fragment-ordered
//   [65536,..) INIT  = bf16(W_init [:, :128])
//   [131072,.) L0    = bf16(W_hh_l0)
//   [196608,.) L1    = bf16([W_ih_l1 | W_hh_l1])  K=256
// fragment order: chunk = ((w*4+G)*KK + kk), within chunk: lane*8+j,
//   n = G*128 + w*16 + (lane&15),  k = kk*32 + (lane>>4)*8 + j
__global__ void pack_w(const float* __restrict__ Winit, const float* __restrict__ Wihl0,
                       const float* __restrict__ Whhl0, const float* __restrict__ Wihl1,
                       const float* __restrict__ Whhl1, unsigned short* __restrict__ pk,
                       int ncopy) {
    int id = blockIdx.x * 256 + threadIdx.x;
    if (id >= 327680) return;
    float v;
    if (id < 131072) {                       // PRE0 / INIT (stride 129, KK=4)
        int e = id & 65535;
        int c = e >> 9, r = e & 511;
        int lane = r >> 3, j = r & 7;
        int kk = c & 3, G = (c >> 2) & 3, w = c >> 4;
        int n = G * 128 + w * 16 + (lane & 15);
        int k = kk * 32 + (lane >> 4) * 8 + j;
        const float* W = (id >> 16) ? Winit : Wihl0;
        v = W[n * 129 + k];
    } else if (id < 196608) {                // L0 (stride 128, KK=4)
        int e = id - 131072;
        int c = e >> 9, r = e & 511;
        int lane = r >> 3, j = r & 7;
        int kk = c & 3, G = (c >> 2) & 3, w = c >> 4;
        int n = G * 128 + w * 16 + (lane & 15);
        int k = kk * 32 + (lane >> 4) * 8 + j;
        v = Whhl0[n * 128 + k];
    } else {                                 // L1 (K=256, KK=8)
        int e = id - 196608;
        int c = e >> 9, r = e & 511;
        int lane = r >> 3, j = r & 7;
        int kk = c & 7, G = (c >> 3) & 3, w = c >> 5;
        int n = G * 128 + w * 16 + (lane & 15);
        int k = kk * 32 + (lane >> 4) * 8 + j;
        v = (k < 128) ? Wihl1[n * 128 + k] : Whhl1[n * 128 + (k - 128)];
    }
    unsigned short hv = f2bf(v);
    for (int cpy = 0; cpy < ncopy; ++cpy) pk[cpy * 327680 + id] = hv;
}

// ---------------- fused decoder kernel ----------------
// block: 512 thr (8 waves), Mt=64 samples. wave w owns hidden cols [16w,16w+16)
// across all 4 gates -> LSTM pointwise is lane-local in MFMA C-layout.
// h1/h2: bf16 in LDS, rows 128 bf16 (256B), XOR chunk swizzle -> <=2-way banks.
// Weights read from per-XCD replica pk + (blockIdx%ncopy)*327680 -> local-L2 hits.
__global__ __launch_bounds__(512, 2)
void traj_main(const float* __restrict__ fused, const float* __restrict__ intent,
               const float* __restrict__ Winit, const float* __restrict__ binit,
               const float* __restrict__ Wihl0, const float* __restrict__ bihl0,
               const float* __restrict__ bhhl0, const float* __restrict__ bihl1,
               const float* __restrict__ bhhl1, const float* __restrict__ Wout,
               const float* __restrict__ bout, const unsigned short* __restrict__ pk,
               int copyMask, float* __restrict__ out, int Bsz) {
    __shared__ __align__(16) unsigned short s_h1[64 * 128];
    __shared__ __align__(16) unsigned short s_h2[64 * 128];
    __shared__ __align__(16) unsigned short s_ct[2 * 64 * 128];   // c-init staging; later aliased as out staging
    __shared__ float s_wo[256];                                    // W_out copy (2x128)

    float* s_out = (float*)s_ct;   // 1536 floats, alias (disjoint lifetime vs c-staging)

    const int tid = threadIdx.x;
    const int lane = tid & 63;
    const int w = tid >> 6;          // wave 0..7
    const int nq = lane & 15;
    const int quad = lane >> 4;
    const int m0 = blockIdx.x * 64;
    const int Bh = Bsz >> 1;

    const unsigned short* pkb = pk + (int)(blockIdx.x & copyMask) * 327680;
    const unsigned short* pkPRE = pkb;
    const unsigned short* pkINI = pkb + 65536;
    const unsigned short* pkL0  = pkb + 131072;
    const unsigned short* pkL1  = pkb + 196608;

    if (tid < 256) s_wo[tid] = Wout[tid];
    const float bo = (tid < 128) ? bout[tid & 1] : 0.0f;

    // per-lane column constants (n = G*128 + 16w + nq)
    float bpre[4], bl1[4], wcp[4], wci[4], bini[4];
#pragma unroll
    for (int G = 0; G < 4; ++G) {
        int n = G * 128 + w * 16 + nq;
        bpre[G] = bihl0[n] + bhhl0[n];
        bl1[G]  = bihl1[n] + bhhl1[n];
        wcp[G]  = Wihl0[n * 129 + 128];    // intent column
        wci[G]  = Winit[n * 129 + 128];
        bini[G] = binit[n];
    }

    // ---- stage x tile as bf16 (swizzled): rows 0..63 own samples -> s_h1,
    //      rows 64..95 init rows m0/2.., rows 96..127 init rows B/2+m0/2.. -> s_h2
#pragma unroll
    for (int it = 0; it < 8; ++it) {
        int f = it * 512 + tid;
        int row = f >> 5, fc = f & 31;
        int g = (row < 64) ? (m0 + row)
                           : ((row < 96) ? ((m0 >> 1) + (row - 64))
                                         : (Bh + (m0 >> 1) + (row - 96)));
        f32x4 v = *(const f32x4*)(fused + g * 128 + fc * 4);
        us4 u;
#pragma unroll
        for (int j = 0; j < 4; ++j) u[j] = f2bf(v[j]);
        int m = row & 63;
        int cp = (fc >> 1) ^ (m & 15);
        unsigned short* buf = (row < 64) ? s_h1 : s_h2;
        *(us4*)&buf[m * 128 + cp * 8 + (fc & 1) * 4] = u;
    }
    __syncthreads();

    // ---- phase A: pre0 = x@Wihl0^T (+b,+intent), initacc = x'@Winit^T (+b,+intent)
    f32x4 pre0[4][4], acc2[4][4];
#pragma unroll
    for (int mt = 0; mt < 4; ++mt)
#pragma unroll
        for (int G = 0; G < 4; ++G) {
            pre0[mt][G] = (f32x4){0.f, 0.f, 0.f, 0.f};
            acc2[mt][G] = (f32x4){0.f, 0.f, 0.f, 0.f};
        }
#pragma unroll
    for (int kk = 0; kk < 4; ++kk) {
        bf16x8 a[4], b[4], a2[4], b2[4];
#pragma unroll
        for (int mt = 0; mt < 4; ++mt) {
            int idx = (mt * 16 + nq) * 128 + (((kk * 4 + quad) ^ nq) << 3);
            a[mt]  = *(const bf16x8*)&s_h1[idx];
            a2[mt] = *(const bf16x8*)&s_h2[idx];
        }
#pragma unroll
        for (int G = 0; G < 4; ++G) {
            int off = ((w * 4 + G) * 4 + kk) * 512 + lane * 8;
            b[G]  = *(const bf16x8*)&pkPRE[off];
            b2[G] = *(const bf16x8*)&pkINI[off];
        }
#pragma unroll
        for (int mt = 0; mt < 4; ++mt)
#pragma unroll
            for (int G = 0; G < 4; ++G) {
                pre0[mt][G] = __builtin_amdgcn_mfma_f32_16x16x32_bf16(a[mt],  b[G],  pre0[mt][G], 0, 0, 0);
                acc2[mt][G] = __builtin_amdgcn_mfma_f32_16x16x32_bf16(a2[mt], b2[G], acc2[mt][G], 0, 0, 0);
            }
    }
#pragma unroll
    for (int mt = 0; mt < 4; ++mt)
#pragma unroll
        for (int r = 0; r < 4; ++r) {
            int ml = mt * 16 + quad * 4 + r;
            float iv = intent[m0 + ml];
            int grow = (mt < 2) ? ((m0 >> 1) + ml) : (Bh + (m0 >> 1) + (ml - 32));
            float iv2 = intent[grow];
#pragma unroll
            for (int G = 0; G < 4; ++G) {
                pre0[mt][G][r] += bpre[G] + iv * wcp[G];
                acc2[mt][G][r] += bini[G] + iv2 * wci[G];
            }
        }
    __syncthreads();   // x-tile reads complete

    // ---- unpack init (torch-faithful flat reshape):
    // init row r=(m>>1): G0=[0:128)->h even, G1->h odd, G2->c even, G3->c odd;
    // mt 0,1 -> layer0, mt 2,3 -> layer1
    {
        int kq = w * 16 + nq, kc = kq >> 3, klo = kq & 7;
#pragma unroll
        for (int mt = 0; mt < 4; ++mt)
#pragma unroll
            for (int r = 0; r < 4; ++r) {
                int ri = mt * 16 + quad * 4 + r;
                int layer = mt >> 1;
                int ril = ri & 31;
#pragma unroll
                for (int G = 0; G < 4; ++G) {
                    int ml = 2 * ril + (G & 1);
                    unsigned short hv = f2bf(acc2[mt][G][r]);
                    if (G < 2) {
                        unsigned short* hb = layer ? s_h2 : s_h1;
                        hb[ml * 128 + ((kc ^ (ml & 15)) << 3) + klo] = hv;
                    } else {
                        s_ct[(layer * 64 + ml) * 128 + kq] = hv;
                    }
                }
            }
    }
    __syncthreads();

    // ---- load c into C-layout registers
    f32x4 c1v[4], c2v[4];
    {
        int kq = w * 16 + nq;
#pragma unroll
        for (int mt = 0; mt < 4; ++mt)
#pragma unroll
            for (int r = 0; r < 4; ++r) {
                int ml = mt * 16 + quad * 4 + r;
                c1v[mt][r] = bf2f(s_ct[ml * 128 + kq]);
                c2v[mt][r] = bf2f(s_ct[(64 + ml) * 128 + kq]);
            }
    }

    // ---- 12 decode steps, state resident
    for (int s = 0; s < SEQ; ++s) {
        f32x4 acc[4][4];
        // layer0: g = pre0 + h1 @ Whhl0^T
#pragma unroll
        for (int mt = 0; mt < 4; ++mt)
#pragma unroll
            for (int G = 0; G < 4; ++G) acc[mt][G] = pre0[mt][G];
#pragma unroll
        for (int kk = 0; kk < 4; ++kk) {
            bf16x8 a[4], b[4];
#pragma unroll
            for (int mt = 0; mt < 4; ++mt)
                a[mt] = *(const bf16x8*)&s_h1[(mt * 16 + nq) * 128 + (((kk * 4 + quad) ^ nq) << 3)];
#pragma unroll
            for (int G = 0; G < 4; ++G)
                b[G] = *(const bf16x8*)&pkL0[((w * 4 + G) * 4 + kk) * 512 + lane * 8];
#pragma unroll
            for (int mt = 0; mt < 4; ++mt)
#pragma unroll
                for (int G = 0; G < 4; ++G)
                    acc[mt][G] = __builtin_amdgcn_mfma_f32_16x16x32_bf16(a[mt], b[G], acc[mt][G], 0, 0, 0);
        }
        __syncthreads();   // B1: h1 reads done
#pragma unroll
        for (int mt = 0; mt < 4; ++mt)
#pragma unroll
            for (int r = 0; r < 4; ++r) {
                float iv = acc[mt][0][r], fv = acc[mt][1][r], gv = acc[mt][2][r], ov = acc[mt][3][r];
                float c = c1v[mt][r];
                float cn = sigf(fv) * c + sigf(iv) * tanhf_(gv);
                float hn = sigf(ov) * tanhf_(cn);
                c1v[mt][r] = cn;
                int ml = mt * 16 + quad * 4 + r;
                s_h1[ml * 128 + ((((w * 2) + (nq >> 3)) ^ (quad * 4 + r)) << 3) + (nq & 7)] = f2bf(hn);
            }
        __syncthreads();   // B2: new h1 visible
        // layer1: g = b1 + [h1_new | h2] @ [Wihl1 | Whhl1]^T   (K=256)
#pragma unroll
        for (int mt = 0; mt < 4; ++mt)
#pragma unroll
            for (int G = 0; G < 4; ++G)
                acc[mt][G] = (f32x4){bl1[G], bl1[G], bl1[G], bl1[G]};
#pragma unroll
        for (int kk = 0; kk < 8; ++kk) {
            const unsigned short* hb = (kk < 4) ? s_h1 : s_h2;
            int kkl = kk & 3;
            bf16x8 a[4], b[4];
#pragma unroll
            for (int mt = 0; mt < 4; ++mt)
                a[mt] = *(const bf16x8*)&hb[(mt * 16 + nq) * 128 + (((kkl * 4 + quad) ^ nq) << 3)];
#pragma unroll
            for (int G = 0; G < 4; ++G)
                b[G] = *(const bf16x8*)&pkL1[((w * 4 + G) * 8 + kk) * 512 + lane * 8];
#pragma unroll
            for (int mt = 0; mt < 4; ++mt)
#pragma unroll
                for (int G = 0; G < 4; ++G)
                    acc[mt][G] = __builtin_amdgcn_mfma_f32_16x16x32_bf16(a[mt], b[G], acc[mt][G], 0, 0, 0);
        }
        __syncthreads();   // B3: h2 reads done
#pragma unroll
        for (int mt = 0; mt < 4; ++mt)
#pragma unroll
            for (int r = 0; r < 4; ++r) {
                float iv = acc[mt][0][r], fv = acc[mt][1][r], gv = acc[mt][2][r], ov = acc[mt][3][r];
                float c = c2v[mt][r];
                float cn = sigf(fv) * c + sigf(iv) * tanhf_(gv);
                float hn = sigf(ov) * tanhf_(cn);
                c2v[mt][r] = cn;
                int ml = mt * 16 + quad * 4 + r;
                s_h2[ml * 128 + ((((w * 2) + (nq >> 3)) ^ (quad * 4 + r)) << 3) + (nq & 7)] = f2bf(hn);
            }
        __syncthreads();   // B4: new h2 visible
        // output head (fp32): stash h2_new @ Wout^T + bout into LDS staging
        if (tid < 128) {
            int ml = tid >> 1, oc = tid & 1;
            const float* wr = s_wo + oc * 128;
            float s0 = 0.f, s1 = 0.f;
            int mx = ml & 15;
#pragma unroll
            for (int c = 0; c < 16; ++c) {
                int base = ml * 128 + ((c ^ mx) << 3);
                int k0 = c << 3;
#pragma unroll
                for (int j = 0; j < 8; j += 2) {
                    unsigned u = *(const unsigned*)&s_h2[base + j];
                    s0 += bf2f((unsigned short)u) * wr[k0 + j];
                    s1 += bf2f((unsigned short)(u >> 16)) * wr[k0 + j + 1];
                }
            }
            s_out[ml * 24 + s * 2 + oc] = s0 + s1 + bo;
        }
    }
    __syncthreads();
    // single contiguous coalesced store: 64 samples x 24 floats = 6 KB
    for (int i = tid; i < 1536; i += 512) out[m0 * 24 + i] = s_out[i];
}

extern "C" void kernel_launch(void* const* d_in, const int* in_sizes, int n_in,
                              void* d_out, int out_size, void* d_ws, size_t ws_size,
                              hipStream_t stream) {
    const float* fused  = (const float*)d_in[0];
    const float* intent = (const float*)d_in[1];
    const float* Winit  = (const float*)d_in[2];
    const float* binit  = (const float*)d_in[3];
    const float* Wihl0  = (const float*)d_in[4];
    const float* Whhl0  = (const float*)d_in[5];
    const float* bihl0  = (const float*)d_in[6];
    const float* bhhl0  = (const float*)d_in[7];
    const float* Wihl1  = (const float*)d_in[8];
    const float* Whhl1  = (const float*)d_in[9];
    const float* bihl1  = (const float*)d_in[10];
    const float* bhhl1  = (const float*)d_in[11];
    const float* Wout   = (const float*)d_in[12];
    const float* bout   = (const float*)d_in[13];
    int Bsz = in_sizes[0] / 128;

    // replicate packed weights: 1 copy per XCD (pow2 <= 8, limited by ws_size)
    int ncopy = 1;
    while (ncopy < 8 && (size_t)(ncopy * 2) * 655360ull <= ws_size) ncopy <<= 1;

    unsigned short* pkw = (unsigned short*)d_ws;   // ncopy * 640 KB used
    pack_w<<<1280, 256, 0, stream>>>(Winit, Wihl0, Whhl0, Wihl1, Whhl1, pkw, ncopy);
    traj_main<<<Bsz / 64, 512, 0, stream>>>(fused, intent, Winit, binit, Wihl0, bihl0,
                                            bhhl0, bihl1, bhhl1, Wout, bout, pkw,
                                            ncopy - 1, (float*)d_out, Bsz);
}

// Round 3
// 3541.071 us; speedup vs baseline: 1.0467x; 1.0018x over previous
//
#include <hip/hip_runtime.h>

#define SEQ 12

typedef __attribute__((ext_vector_type(8))) short bf16x8;   // 8 bf16 bit patterns (4 VGPRs)
typedef __attribute__((ext_vector_type(4))) float f32x4;
typedef __attribute__((ext_vector_type(4))) unsigned short us4;

__device__ __forceinline__ unsigned short f2bf(float x) {
    unsigned u = __builtin_bit_cast(unsigned, x);
    u += 0x7fffu + ((u >> 16) & 1u);            // round-to-nearest-even
    return (unsigned short)(u >> 16);
}
__device__ __forceinline__ float bf2f(unsigned short h) {
    unsigned u = ((unsigned)h) << 16;
    return __builtin_bit_cast(float, u);
}
__device__ __forceinline__ float sigf(float x) { return 1.0f / (1.0f + __expf(-x)); }
__device__ __forceinline__ float tanhf_(float x) {
    x = fminf(fmaxf(x, -15.0f), 15.0f);
    float e = __expf(2.0f * x);
    return (e - 1.0f) / (e + 1.0f);
}

// ---------------- weight pack kernel ----------------
// d_ws layout (ushort), REPLICATED ncopy times at stride 327680 (640 KB/copy):
//   [0,65536)  PRE0  = bf16(W_ih_l0[:, :128])  fragment-ordered
//   [65536,..) INIT  = bf16(W_init [:, :128])
//   [131072,.) L0    = bf16(W_hh_l0)
//   [196608,.) L1    = bf16([W_ih_l1 | W_hh_l1])  K=256
// fragment order: chunk = ((w*4+G)*KK + kk), within chunk: lane*8+j,
//   n = G*128 + w*16 + (lane&15),  k = kk*32 + (lane>>4)*8 + j
__global__ void pack_w(const float* __restrict__ Winit, const float* __restrict__ Wihl0,
                       const float* __restrict__ Whhl0, const float* __restrict__ Wihl1,
                       const float* __restrict__ Whhl1, unsigned short* __restrict__ pk,
                       int ncopy) {
    int id = blockIdx.x * 256 + threadIdx.x;
    if (id >= 327680) return;
    float v;
    if (id < 131072) {                       // PRE0 / INIT (stride 129, KK=4)
        int e = id & 65535;
        int c = e >> 9, r = e & 511;
        int lane = r >> 3, j = r & 7;
        int kk = c & 3, G = (c >> 2) & 3, w = c >> 4;
        int n = G * 128 + w * 16 + (lane & 15);
        int k = kk * 32 + (lane >> 4) * 8 + j;
        const float* W = (id >> 16) ? Winit : Wihl0;
        v = W[n * 129 + k];
    } else if (id < 196608) {                // L0 (stride 128, KK=4)
        int e = id - 131072;
        int c = e >> 9, r = e & 511;
        int lane = r >> 3, j = r & 7;
        int kk = c & 3, G = (c >> 2) & 3, w = c >> 4;
        int n = G * 128 + w * 16 + (lane & 15);
        int k = kk * 32 + (lane >> 4) * 8 + j;
        v = Whhl0[n * 128 + k];
    } else {                                 // L1 (K=256, KK=8)
        int e = id - 196608;
        int c = e >> 9, r = e & 511;
        int lane = r >> 3, j = r & 7;
        int kk = c & 7, G = (c >> 3) & 3, w = c >> 5;
        int n = G * 128 + w * 16 + (lane & 15);
        int k = kk * 32 + (lane >> 4) * 8 + j;
        v = (k < 128) ? Wihl1[n * 128 + k] : Whhl1[n * 128 + (k - 128)];
    }
    unsigned short hv = f2bf(v);
    for (int cpy = 0; cpy < ncopy; ++cpy) pk[cpy * 327680 + id] = hv;
}

// ---------------- fused decoder kernel ----------------
// block: 512 thr (8 waves), Mt=64 samples. wave w owns hidden cols [16w,16w+16)
// across all 4 gates -> LSTM pointwise is lane-local in MFMA C-layout.
// h1/h2: bf16 in LDS, rows 128 bf16 (256B), XOR chunk swizzle -> <=2-way banks.
// Weights read from per-XCD replica pk + (blockIdx%ncopy)*327680.
// NOTE: no min-waves-per-EU in launch_bounds (let allocator use up to 256 VGPR,
// zero spills); step loop pinned to unroll 1 so the body stays I-cache resident.
__global__ __launch_bounds__(512)
void traj_main(const float* __restrict__ fused, const float* __restrict__ intent,
               const float* __restrict__ Winit, const float* __restrict__ binit,
               const float* __restrict__ Wihl0, const float* __restrict__ bihl0,
               const float* __restrict__ bhhl0, const float* __restrict__ bihl1,
               const float* __restrict__ bhhl1, const float* __restrict__ Wout,
               const float* __restrict__ bout, const unsigned short* __restrict__ pk,
               int copyMask, float* __restrict__ out, int Bsz) {
    __shared__ __align__(16) unsigned short s_h1[64 * 128];
    __shared__ __align__(16) unsigned short s_h2[64 * 128];
    __shared__ __align__(16) unsigned short s_ct[2 * 64 * 128];   // c-init staging; later aliased as out staging
    __shared__ float s_wo[256];                                    // W_out copy (2x128)

    float* s_out = (float*)s_ct;   // 1536 floats, alias (disjoint lifetime vs c-staging)

    const int tid = threadIdx.x;
    const int lane = tid & 63;
    const int w = tid >> 6;          // wave 0..7
    const int nq = lane & 15;
    const int quad = lane >> 4;
    const int m0 = blockIdx.x * 64;
    const int Bh = Bsz >> 1;

    const unsigned short* pkb = pk + (int)(blockIdx.x & copyMask) * 327680;
    const unsigned short* pkPRE = pkb;
    const unsigned short* pkINI = pkb + 65536;
    const unsigned short* pkL0  = pkb + 131072;
    const unsigned short* pkL1  = pkb + 196608;

    if (tid < 256) s_wo[tid] = Wout[tid];
    const float bo = (tid < 128) ? bout[tid & 1] : 0.0f;

    // per-lane column constants (n = G*128 + 16w + nq)
    float bpre[4], bl1[4], wcp[4], wci[4], bini[4];
#pragma unroll
    for (int G = 0; G < 4; ++G) {
        int n = G * 128 + w * 16 + nq;
        bpre[G] = bihl0[n] + bhhl0[n];
        bl1[G]  = bihl1[n] + bhhl1[n];
        wcp[G]  = Wihl0[n * 129 + 128];    // intent column
        wci[G]  = Winit[n * 129 + 128];
        bini[G] = binit[n];
    }

    // ---- stage x tile as bf16 (swizzled): rows 0..63 own samples -> s_h1,
    //      rows 64..95 init rows m0/2.., rows 96..127 init rows B/2+m0/2.. -> s_h2
#pragma unroll
    for (int it = 0; it < 8; ++it) {
        int f = it * 512 + tid;
        int row = f >> 5, fc = f & 31;
        int g = (row < 64) ? (m0 + row)
                           : ((row < 96) ? ((m0 >> 1) + (row - 64))
                                         : (Bh + (m0 >> 1) + (row - 96)));
        f32x4 v = *(const f32x4*)(fused + g * 128 + fc * 4);
        us4 u;
#pragma unroll
        for (int j = 0; j < 4; ++j) u[j] = f2bf(v[j]);
        int m = row & 63;
        int cp = (fc >> 1) ^ (m & 15);
        unsigned short* buf = (row < 64) ? s_h1 : s_h2;
        *(us4*)&buf[m * 128 + cp * 8 + (fc & 1) * 4] = u;
    }
    __syncthreads();

    // ---- phase A: pre0 = x@Wihl0^T (+b,+intent), initacc = x'@Winit^T (+b,+intent)
    f32x4 pre0[4][4], acc2[4][4];
#pragma unroll
    for (int mt = 0; mt < 4; ++mt)
#pragma unroll
        for (int G = 0; G < 4; ++G) {
            pre0[mt][G] = (f32x4){0.f, 0.f, 0.f, 0.f};
            acc2[mt][G] = (f32x4){0.f, 0.f, 0.f, 0.f};
        }
#pragma unroll
    for (int kk = 0; kk < 4; ++kk) {
        bf16x8 a[4], b[4], a2[4], b2[4];
#pragma unroll
        for (int mt = 0; mt < 4; ++mt) {
            int idx = (mt * 16 + nq) * 128 + (((kk * 4 + quad) ^ nq) << 3);
            a[mt]  = *(const bf16x8*)&s_h1[idx];
            a2[mt] = *(const bf16x8*)&s_h2[idx];
        }
#pragma unroll
        for (int G = 0; G < 4; ++G) {
            int off = ((w * 4 + G) * 4 + kk) * 512 + lane * 8;
            b[G]  = *(const bf16x8*)&pkPRE[off];
            b2[G] = *(const bf16x8*)&pkINI[off];
        }
#pragma unroll
        for (int mt = 0; mt < 4; ++mt)
#pragma unroll
            for (int G = 0; G < 4; ++G) {
                pre0[mt][G] = __builtin_amdgcn_mfma_f32_16x16x32_bf16(a[mt],  b[G],  pre0[mt][G], 0, 0, 0);
                acc2[mt][G] = __builtin_amdgcn_mfma_f32_16x16x32_bf16(a2[mt], b2[G], acc2[mt][G], 0, 0, 0);
            }
    }
#pragma unroll
    for (int mt = 0; mt < 4; ++mt)
#pragma unroll
        for (int r = 0; r < 4; ++r) {
            int ml = mt * 16 + quad * 4 + r;
            float iv = intent[m0 + ml];
            int grow = (mt < 2) ? ((m0 >> 1) + ml) : (Bh + (m0 >> 1) + (ml - 32));
            float iv2 = intent[grow];
#pragma unroll
            for (int G = 0; G < 4; ++G) {
                pre0[mt][G][r] += bpre[G] + iv * wcp[G];
                acc2[mt][G][r] += bini[G] + iv2 * wci[G];
            }
        }
    __syncthreads();   // x-tile reads complete

    // ---- unpack init (torch-faithful flat reshape):
    // init row r=(m>>1): G0=[0:128)->h even, G1->h odd, G2->c even, G3->c odd;
    // mt 0,1 -> layer0, mt 2,3 -> layer1
    {
        int kq = w * 16 + nq, kc = kq >> 3, klo = kq & 7;
#pragma unroll
        for (int mt = 0; mt < 4; ++mt)
#pragma unroll
            for (int r = 0; r < 4; ++r) {
                int ri = mt * 16 + quad * 4 + r;
                int layer = mt >> 1;
                int ril = ri & 31;
#pragma unroll
                for (int G = 0; G < 4; ++G) {
                    int ml = 2 * ril + (G & 1);
                    unsigned short hv = f2bf(acc2[mt][G][r]);
                    if (G < 2) {
                        unsigned short* hb = layer ? s_h2 : s_h1;
                        hb[ml * 128 + ((kc ^ (ml & 15)) << 3) + klo] = hv;
                    } else {
                        s_ct[(layer * 64 + ml) * 128 + kq] = hv;
                    }
                }
            }
    }
    __syncthreads();

    // ---- load c into C-layout registers
    f32x4 c1v[4], c2v[4];
    {
        int kq = w * 16 + nq;
#pragma unroll
        for (int mt = 0; mt < 4; ++mt)
#pragma unroll
            for (int r = 0; r < 4; ++r) {
                int ml = mt * 16 + quad * 4 + r;
                c1v[mt][r] = bf2f(s_ct[ml * 128 + kq]);
                c2v[mt][r] = bf2f(s_ct[(64 + ml) * 128 + kq]);
            }
    }

    // ---- 12 decode steps, state resident (unroll 1: keep body I-cache sized)
#pragma unroll 1
    for (int s = 0; s < SEQ; ++s) {
        f32x4 acc[4][4];
        // layer0: g = pre0 + h1 @ Whhl0^T
#pragma unroll
        for (int mt = 0; mt < 4; ++mt)
#pragma unroll
            for (int G = 0; G < 4; ++G) acc[mt][G] = pre0[mt][G];
#pragma unroll
        for (int kk = 0; kk < 4; ++kk) {
            bf16x8 a[4], b[4];
#pragma unroll
            for (int mt = 0; mt < 4; ++mt)
                a[mt] = *(const bf16x8*)&s_h1[(mt * 16 + nq) * 128 + (((kk * 4 + quad) ^ nq) << 3)];
#pragma unroll
            for (int G = 0; G < 4; ++G)
                b[G] = *(const bf16x8*)&pkL0[((w * 4 + G) * 4 + kk) * 512 + lane * 8];
#pragma unroll
            for (int mt = 0; mt < 4; ++mt)
#pragma unroll
                for (int G = 0; G < 4; ++G)
                    acc[mt][G] = __builtin_amdgcn_mfma_f32_16x16x32_bf16(a[mt], b[G], acc[mt][G], 0, 0, 0);
        }
        __syncthreads();   // B1: h1 reads done
#pragma unroll
        for (int mt = 0; mt < 4; ++mt)
#pragma unroll
            for (int r = 0; r < 4; ++r) {
                float iv = acc[mt][0][r], fv = acc[mt][1][r], gv = acc[mt][2][r], ov = acc[mt][3][r];
                float c = c1v[mt][r];
                float cn = sigf(fv) * c + sigf(iv) * tanhf_(gv);
                float hn = sigf(ov) * tanhf_(cn);
                c1v[mt][r] = cn;
                int ml = mt * 16 + quad * 4 + r;
                s_h1[ml * 128 + ((((w * 2) + (nq >> 3)) ^ (quad * 4 + r)) << 3) + (nq & 7)] = f2bf(hn);
            }
        __syncthreads();   // B2: new h1 visible
        // layer1: g = b1 + [h1_new | h2] @ [Wihl1 | Whhl1]^T   (K=256)
#pragma unroll
        for (int mt = 0; mt < 4; ++mt)
#pragma unroll
            for (int G = 0; G < 4; ++G)
                acc[mt][G] = (f32x4){bl1[G], bl1[G], bl1[G], bl1[G]};
#pragma unroll
        for (int kk = 0; kk < 8; ++kk) {
            const unsigned short* hb = (kk < 4) ? s_h1 : s_h2;
            int kkl = kk & 3;
            bf16x8 a[4], b[4];
#pragma unroll
            for (int mt = 0; mt < 4; ++mt)
                a[mt] = *(const bf16x8*)&hb[(mt * 16 + nq) * 128 + (((kkl * 4 + quad) ^ nq) << 3)];
#pragma unroll
            for (int G = 0; G < 4; ++G)
                b[G] = *(const bf16x8*)&pkL1[((w * 4 + G) * 8 + kk) * 512 + lane * 8];
#pragma unroll
            for (int mt = 0; mt < 4; ++mt)
#pragma unroll
                for (int G = 0; G < 4; ++G)
                    acc[mt][G] = __builtin_amdgcn_mfma_f32_16x16x32_bf16(a[mt], b[G], acc[mt][G], 0, 0, 0);
        }
        __syncthreads();   // B3: h2 reads done
#pragma unroll
        for (int mt = 0; mt < 4; ++mt)
#pragma unroll
            for (int r = 0; r < 4; ++r) {
                float iv = acc[mt][0][r], fv = acc[mt][1][r], gv = acc[mt][2][r], ov = acc[mt][3][r];
                float c = c2v[mt][r];
                float cn = sigf(fv) * c + sigf(iv) * tanhf_(gv);
                float hn = sigf(ov) * tanhf_(cn);
                c2v[mt][r] = cn;
                int ml = mt * 16 + quad * 4 + r;
                s_h2[ml * 128 + ((((w * 2) + (nq >> 3)) ^ (quad * 4 + r)) << 3) + (nq & 7)] = f2bf(hn);
            }
        __syncthreads();   // B4: new h2 visible
        // output head (fp32): stash h2_new @ Wout^T + bout into LDS staging
        if (tid < 128) {
            int ml = tid >> 1, oc = tid & 1;
            const float* wr = s_wo + oc * 128;
            float s0 = 0.f, s1 = 0.f;
            int mx = ml & 15;
#pragma unroll
            for (int c = 0; c < 16; ++c) {
                int base = ml * 128 + ((c ^ mx) << 3);
                int k0 = c << 3;
#pragma unroll
                for (int j = 0; j < 8; j += 2) {
                    unsigned u = *(const unsigned*)&s_h2[base + j];
                    s0 += bf2f((unsigned short)u) * wr[k0 + j];
                    s1 += bf2f((unsigned short)(u >> 16)) * wr[k0 + j + 1];
                }
            }
            s_out[ml * 24 + s * 2 + oc] = s0 + s1 + bo;
        }
    }
    __syncthreads();
    // single contiguous coalesced store: 64 samples x 24 floats = 6 KB
    for (int i = tid; i < 1536; i += 512) out[m0 * 24 + i] = s_out[i];
}

extern "C" void kernel_launch(void* const* d_in, const int* in_sizes, int n_in,
                              void* d_out, int out_size, void* d_ws, size_t ws_size,
                              hipStream_t stream) {
    const float* fused  = (const float*)d_in[0];
    const float* intent = (const float*)d_in[1];
    const float* Winit  = (const float*)d_in[2];
    const float* binit  = (const float*)d_in[3];
    const float* Wihl0  = (const float*)d_in[4];
    const float* Whhl0  = (const float*)d_in[5];
    const float* bihl0  = (const float*)d_in[6];
    const float* bhhl0  = (const float*)d_in[7];
    const float* Wihl1  = (const float*)d_in[8];
    const float* Whhl1  = (const float*)d_in[9];
    const float* bihl1  = (const float*)d_in[10];
    const float* bhhl1  = (const float*)d_in[11];
    const float* Wout   = (const float*)d_in[12];
    const float* bout   = (const float*)d_in[13];
    int Bsz = in_sizes[0] / 128;

    // replicate packed weights: 1 copy per XCD (pow2 <= 8, limited by ws_size)
    int ncopy = 1;
    while (ncopy < 8 && (size_t)(ncopy * 2) * 655360ull <= ws_size) ncopy <<= 1;

    unsigned short* pkw = (unsigned short*)d_ws;   // ncopy * 640 KB used
    pack_w<<<1280, 256, 0, stream>>>(Winit, Wihl0, Whhl0, Wihl1, Whhl1, pkw, ncopy);
    traj_main<<<Bsz / 64, 512, 0, stream>>>(fused, intent, Winit, binit, Wihl0, bihl0,
                                            bhhl0, bihl1, bhhl1, Wout, bout, pkw,
                                            ncopy - 1, (float*)d_out, Bsz);
}

// Round 4
// 3532.916 us; speedup vs baseline: 1.0491x; 1.0023x over previous
//
#include <hip/hip_runtime.h>

#define SEQ 12

typedef __attribute__((ext_vector_type(8))) short bf16x8;   // 8 bf16 bit patterns (4 VGPRs)
typedef __attribute__((ext_vector_type(4))) float f32x4;
typedef __attribute__((ext_vector_type(4))) unsigned short us4;

__device__ __forceinline__ unsigned short f2bf(float x) {
    unsigned u = __builtin_bit_cast(unsigned, x);
    u += 0x7fffu + ((u >> 16) & 1u);            // round-to-nearest-even
    return (unsigned short)(u >> 16);
}
__device__ __forceinline__ float bf2f(unsigned short h) {
    unsigned u = ((unsigned)h) << 16;
    return __builtin_bit_cast(float, u);
}
__device__ __forceinline__ float sigf(float x) { return 1.0f / (1.0f + __expf(-x)); }
__device__ __forceinline__ float tanhf_(float x) {
    x = fminf(fmaxf(x, -15.0f), 15.0f);
    float e = __expf(2.0f * x);
    return (e - 1.0f) / (e + 1.0f);
}

// ---------------- weight pack kernel ----------------
// d_ws layout (ushort), REPLICATED ncopy times at stride 327680 (640 KB/copy):
//   [0,65536)  PRE0  = bf16(W_ih_l0[:, :128])  fragment-ordered
//   [65536,..) INIT  = bf16(W_init [:, :128])
//   [131072,.) L0    = bf16(W_hh_l0)
//   [196608,.) L1    = bf16([W_ih_l1 | W_hh_l1])  K=256
// fragment order: chunk = ((w*4+G)*KK + kk), within chunk: lane*8+j,
//   n = G*128 + w*16 + (lane&15),  k = kk*32 + (lane>>4)*8 + j
__global__ void pack_w(const float* __restrict__ Winit, const float* __restrict__ Wihl0,
                       const float* __restrict__ Whhl0, const float* __restrict__ Wihl1,
                       const float* __restrict__ Whhl1, unsigned short* __restrict__ pk,
                       int ncopy) {
    int id = blockIdx.x * 256 + threadIdx.x;
    if (id >= 327680) return;
    float v;
    if (id < 131072) {                       // PRE0 / INIT (stride 129, KK=4)
        int e = id & 65535;
        int c = e >> 9, r = e & 511;
        int lane = r >> 3, j = r & 7;
        int kk = c & 3, G = (c >> 2) & 3, w = c >> 4;
        int n = G * 128 + w * 16 + (lane & 15);
        int k = kk * 32 + (lane >> 4) * 8 + j;
        const float* W = (id >> 16) ? Winit : Wihl0;
        v = W[n * 129 + k];
    } else if (id < 196608) {                // L0 (stride 128, KK=4)
        int e = id - 131072;
        int c = e >> 9, r = e & 511;
        int lane = r >> 3, j = r & 7;
        int kk = c & 3, G = (c >> 2) & 3, w = c >> 4;
        int n = G * 128 + w * 16 + (lane & 15);
        int k = kk * 32 + (lane >> 4) * 8 + j;
        v = Whhl0[n * 128 + k];
    } else {                                 // L1 (K=256, KK=8)
        int e = id - 196608;
        int c = e >> 9, r = e & 511;
        int lane = r >> 3, j = r & 7;
        int kk = c & 7, G = (c >> 3) & 3, w = c >> 5;
        int n = G * 128 + w * 16 + (lane & 15);
        int k = kk * 32 + (lane >> 4) * 8 + j;
        v = (k < 128) ? Wihl1[n * 128 + k] : Whhl1[n * 128 + (k - 128)];
    }
    unsigned short hv = f2bf(v);
    for (int cpy = 0; cpy < ncopy; ++cpy) pk[cpy * 327680 + id] = hv;
}

// ---------------- fused decoder kernel ----------------
// block: 512 thr (8 waves), Mt=64 samples. wave w owns hidden cols [16w,16w+16)
// across all 4 gates -> LSTM pointwise is lane-local in MFMA C-layout.
// h1/h2: bf16 in LDS, rows 128 bf16 (256B), XOR chunk swizzle -> <=2-way banks.
// Weights read from per-XCD replica pk + (blockIdx%ncopy)*327680.
// amdgpu_waves_per_eu(2,2): pin occupancy target to 2 waves/SIMD so the
// allocator gets a 256-VGPR budget (state needs ~230-260) instead of spilling
// ~100 regs/thread to scratch to chase its default occupancy heuristic.
__global__ __launch_bounds__(512) __attribute__((amdgpu_waves_per_eu(2, 2)))
void traj_main(const float* __restrict__ fused, const float* __restrict__ intent,
               const float* __restrict__ Winit, const float* __restrict__ binit,
               const float* __restrict__ Wihl0, const float* __restrict__ bihl0,
               const float* __restrict__ bhhl0, const float* __restrict__ bihl1,
               const float* __restrict__ bhhl1, const float* __restrict__ Wout,
               const float* __restrict__ bout, const unsigned short* __restrict__ pk,
               int copyMask, float* __restrict__ out, int Bsz) {
    __shared__ __align__(16) unsigned short s_h1[64 * 128];
    __shared__ __align__(16) unsigned short s_h2[64 * 128];
    __shared__ __align__(16) unsigned short s_ct[2 * 64 * 128];   // c-init staging; later aliased as out staging
    __shared__ float s_wo[256];                                    // W_out copy (2x128)

    float* s_out = (float*)s_ct;   // 1536 floats, alias (disjoint lifetime vs c-staging)

    const int tid = threadIdx.x;
    const int lane = tid & 63;
    const int w = tid >> 6;          // wave 0..7
    const int nq = lane & 15;
    const int quad = lane >> 4;
    const int m0 = blockIdx.x * 64;
    const int Bh = Bsz >> 1;

    const unsigned short* pkb = pk + (int)(blockIdx.x & copyMask) * 327680;
    const unsigned short* pkPRE = pkb;
    const unsigned short* pkINI = pkb + 65536;
    const unsigned short* pkL0  = pkb + 131072;
    const unsigned short* pkL1  = pkb + 196608;

    if (tid < 256) s_wo[tid] = Wout[tid];
    const float bo = (tid < 128) ? bout[tid & 1] : 0.0f;

    // per-lane column constants (n = G*128 + 16w + nq)
    float bpre[4], bl1[4], wcp[4], wci[4], bini[4];
#pragma unroll
    for (int G = 0; G < 4; ++G) {
        int n = G * 128 + w * 16 + nq;
        bpre[G] = bihl0[n] + bhhl0[n];
        bl1[G]  = bihl1[n] + bhhl1[n];
        wcp[G]  = Wihl0[n * 129 + 128];    // intent column
        wci[G]  = Winit[n * 129 + 128];
        bini[G] = binit[n];
    }

    // ---- stage x tile as bf16 (swizzled): rows 0..63 own samples -> s_h1,
    //      rows 64..95 init rows m0/2.., rows 96..127 init rows B/2+m0/2.. -> s_h2
#pragma unroll
    for (int it = 0; it < 8; ++it) {
        int f = it * 512 + tid;
        int row = f >> 5, fc = f & 31;
        int g = (row < 64) ? (m0 + row)
                           : ((row < 96) ? ((m0 >> 1) + (row - 64))
                                         : (Bh + (m0 >> 1) + (row - 96)));
        f32x4 v = *(const f32x4*)(fused + g * 128 + fc * 4);
        us4 u;
#pragma unroll
        for (int j = 0; j < 4; ++j) u[j] = f2bf(v[j]);
        int m = row & 63;
        int cp = (fc >> 1) ^ (m & 15);
        unsigned short* buf = (row < 64) ? s_h1 : s_h2;
        *(us4*)&buf[m * 128 + cp * 8 + (fc & 1) * 4] = u;
    }
    __syncthreads();

    // ---- phase A: pre0 = x@Wihl0^T (+b,+intent), initacc = x'@Winit^T (+b,+intent)
    f32x4 pre0[4][4], acc2[4][4];
#pragma unroll
    for (int mt = 0; mt < 4; ++mt)
#pragma unroll
        for (int G = 0; G < 4; ++G) {
            pre0[mt][G] = (f32x4){0.f, 0.f, 0.f, 0.f};
            acc2[mt][G] = (f32x4){0.f, 0.f, 0.f, 0.f};
        }
#pragma unroll
    for (int kk = 0; kk < 4; ++kk) {
        bf16x8 a[4], b[4], a2[4], b2[4];
#pragma unroll
        for (int mt = 0; mt < 4; ++mt) {
            int idx = (mt * 16 + nq) * 128 + (((kk * 4 + quad) ^ nq) << 3);
            a[mt]  = *(const bf16x8*)&s_h1[idx];
            a2[mt] = *(const bf16x8*)&s_h2[idx];
        }
#pragma unroll
        for (int G = 0; G < 4; ++G) {
            int off = ((w * 4 + G) * 4 + kk) * 512 + lane * 8;
            b[G]  = *(const bf16x8*)&pkPRE[off];
            b2[G] = *(const bf16x8*)&pkINI[off];
        }
#pragma unroll
        for (int mt = 0; mt < 4; ++mt)
#pragma unroll
            for (int G = 0; G < 4; ++G) {
                pre0[mt][G] = __builtin_amdgcn_mfma_f32_16x16x32_bf16(a[mt],  b[G],  pre0[mt][G], 0, 0, 0);
                acc2[mt][G] = __builtin_amdgcn_mfma_f32_16x16x32_bf16(a2[mt], b2[G], acc2[mt][G], 0, 0, 0);
            }
    }
#pragma unroll
    for (int mt = 0; mt < 4; ++mt)
#pragma unroll
        for (int r = 0; r < 4; ++r) {
            int ml = mt * 16 + quad * 4 + r;
            float iv = intent[m0 + ml];
            int grow = (mt < 2) ? ((m0 >> 1) + ml) : (Bh + (m0 >> 1) + (ml - 32));
            float iv2 = intent[grow];
#pragma unroll
            for (int G = 0; G < 4; ++G) {
                pre0[mt][G][r] += bpre[G] + iv * wcp[G];
                acc2[mt][G][r] += bini[G] + iv2 * wci[G];
            }
        }
    __syncthreads();   // x-tile reads complete

    // ---- unpack init (torch-faithful flat reshape):
    // init row r=(m>>1): G0=[0:128)->h even, G1->h odd, G2->c even, G3->c odd;
    // mt 0,1 -> layer0, mt 2,3 -> layer1
    {
        int kq = w * 16 + nq, kc = kq >> 3, klo = kq & 7;
#pragma unroll
        for (int mt = 0; mt < 4; ++mt)
#pragma unroll
            for (int r = 0; r < 4; ++r) {
                int ri = mt * 16 + quad * 4 + r;
                int layer = mt >> 1;
                int ril = ri & 31;
#pragma unroll
                for (int G = 0; G < 4; ++G) {
                    int ml = 2 * ril + (G & 1);
                    unsigned short hv = f2bf(acc2[mt][G][r]);
                    if (G < 2) {
                        unsigned short* hb = layer ? s_h2 : s_h1;
                        hb[ml * 128 + ((kc ^ (ml & 15)) << 3) + klo] = hv;
                    } else {
                        s_ct[(layer * 64 + ml) * 128 + kq] = hv;
                    }
                }
            }
    }
    __syncthreads();

    // ---- load c into C-layout registers
    f32x4 c1v[4], c2v[4];
    {
        int kq = w * 16 + nq;
#pragma unroll
        for (int mt = 0; mt < 4; ++mt)
#pragma unroll
            for (int r = 0; r < 4; ++r) {
                int ml = mt * 16 + quad * 4 + r;
                c1v[mt][r] = bf2f(s_ct[ml * 128 + kq]);
                c2v[mt][r] = bf2f(s_ct[(64 + ml) * 128 + kq]);
            }
    }

    // ---- 12 decode steps, state resident (unroll 1: keep body I-cache sized)
#pragma unroll 1
    for (int s = 0; s < SEQ; ++s) {
        f32x4 acc[4][4];
        // layer0: g = pre0 + h1 @ Whhl0^T
#pragma unroll
        for (int mt = 0; mt < 4; ++mt)
#pragma unroll
            for (int G = 0; G < 4; ++G) acc[mt][G] = pre0[mt][G];
#pragma unroll
        for (int kk = 0; kk < 4; ++kk) {
            bf16x8 a[4], b[4];
#pragma unroll
            for (int mt = 0; mt < 4; ++mt)
                a[mt] = *(const bf16x8*)&s_h1[(mt * 16 + nq) * 128 + (((kk * 4 + quad) ^ nq) << 3)];
#pragma unroll
            for (int G = 0; G < 4; ++G)
                b[G] = *(const bf16x8*)&pkL0[((w * 4 + G) * 4 + kk) * 512 + lane * 8];
#pragma unroll
            for (int mt = 0; mt < 4; ++mt)
#pragma unroll
                for (int G = 0; G < 4; ++G)
                    acc[mt][G] = __builtin_amdgcn_mfma_f32_16x16x32_bf16(a[mt], b[G], acc[mt][G], 0, 0, 0);
        }
        __syncthreads();   // B1: h1 reads done
#pragma unroll
        for (int mt = 0; mt < 4; ++mt)
#pragma unroll
            for (int r = 0; r < 4; ++r) {
                float iv = acc[mt][0][r], fv = acc[mt][1][r], gv = acc[mt][2][r], ov = acc[mt][3][r];
                float c = c1v[mt][r];
                float cn = sigf(fv) * c + sigf(iv) * tanhf_(gv);
                float hn = sigf(ov) * tanhf_(cn);
                c1v[mt][r] = cn;
                int ml = mt * 16 + quad * 4 + r;
                s_h1[ml * 128 + ((((w * 2) + (nq >> 3)) ^ (quad * 4 + r)) << 3) + (nq & 7)] = f2bf(hn);
            }
        __syncthreads();   // B2: new h1 visible
        // layer1: g = b1 + [h1_new | h2] @ [Wihl1 | Whhl1]^T   (K=256)
#pragma unroll
        for (int mt = 0; mt < 4; ++mt)
#pragma unroll
            for (int G = 0; G < 4; ++G)
                acc[mt][G] = (f32x4){bl1[G], bl1[G], bl1[G], bl1[G]};
#pragma unroll
        for (int kk = 0; kk < 8; ++kk) {
            const unsigned short* hb = (kk < 4) ? s_h1 : s_h2;
            int kkl = kk & 3;
            bf16x8 a[4], b[4];
#pragma unroll
            for (int mt = 0; mt < 4; ++mt)
                a[mt] = *(const bf16x8*)&hb[(mt * 16 + nq) * 128 + (((kkl * 4 + quad) ^ nq) << 3)];
#pragma unroll
            for (int G = 0; G < 4; ++G)
                b[G] = *(const bf16x8*)&pkL1[((w * 4 + G) * 8 + kk) * 512 + lane * 8];
#pragma unroll
            for (int mt = 0; mt < 4; ++mt)
#pragma unroll
                for (int G = 0; G < 4; ++G)
                    acc[mt][G] = __builtin_amdgcn_mfma_f32_16x16x32_bf16(a[mt], b[G], acc[mt][G], 0, 0, 0);
        }
        __syncthreads();   // B3: h2 reads done
#pragma unroll
        for (int mt = 0; mt < 4; ++mt)
#pragma unroll
            for (int r = 0; r < 4; ++r) {
                float iv = acc[mt][0][r], fv = acc[mt][1][r], gv = acc[mt][2][r], ov = acc[mt][3][r];
                float c = c2v[mt][r];
                float cn = sigf(fv) * c + sigf(iv) * tanhf_(gv);
                float hn = sigf(ov) * tanhf_(cn);
                c2v[mt][r] = cn;
                int ml = mt * 16 + quad * 4 + r;
                s_h2[ml * 128 + ((((w * 2) + (nq >> 3)) ^ (quad * 4 + r)) << 3) + (nq & 7)] = f2bf(hn);
            }
        __syncthreads();   // B4: new h2 visible
        // output head (fp32): stash h2_new @ Wout^T + bout into LDS staging
        if (tid < 128) {
            int ml = tid >> 1, oc = tid & 1;
            const float* wr = s_wo + oc * 128;
            float s0 = 0.f, s1 = 0.f;
            int mx = ml & 15;
#pragma unroll
            for (int c = 0; c < 16; ++c) {
                int base = ml * 128 + ((c ^ mx) << 3);
                int k0 = c << 3;
#pragma unroll
                for (int j = 0; j < 8; j += 2) {
                    unsigned u = *(const unsigned*)&s_h2[base + j];
                    s0 += bf2f((unsigned short)u) * wr[k0 + j];
                    s1 += bf2f((unsigned short)(u >> 16)) * wr[k0 + j + 1];
                }
            }
            s_out[ml * 24 + s * 2 + oc] = s0 + s1 + bo;
        }
    }
    __syncthreads();
    // single contiguous coalesced store: 64 samples x 24 floats = 6 KB
    for (int i = tid; i < 1536; i += 512) out[m0 * 24 + i] = s_out[i];
}

extern "C" void kernel_launch(void* const* d_in, const int* in_sizes, int n_in,
                              void* d_out, int out_size, void* d_ws, size_t ws_size,
                              hipStream_t stream) {
    const float* fused  = (const float*)d_in[0];
    const float* intent = (const float*)d_in[1];
    const float* Winit  = (const float*)d_in[2];
    const float* binit  = (const float*)d_in[3];
    const float* Wihl0  = (const float*)d_in[4];
    const float* Whhl0  = (const float*)d_in[5];
    const float* bihl0  = (const float*)d_in[6];
    const float* bhhl0  = (const float*)d_in[7];
    const float* Wihl1  = (const float*)d_in[8];
    const float* Whhl1  = (const float*)d_in[9];
    const float* bihl1  = (const float*)d_in[10];
    const float* bhhl1  = (const float*)d_in[11];
    const float* Wout   = (const float*)d_in[12];
    const float* bout   = (const float*)d_in[13];
    int Bsz = in_sizes[0] / 128;

    // replicate packed weights: 1 copy per XCD (pow2 <= 8, limited by ws_size)
    int ncopy = 1;
    while (ncopy < 8 && (size_t)(ncopy * 2) * 655360ull <= ws_size) ncopy <<= 1;

    unsigned short* pkw = (unsigned short*)d_ws;   // ncopy * 640 KB used
    pack_w<<<1280, 256, 0, stream>>>(Winit, Wihl0, Whhl0, Wihl1, Whhl1, pkw, ncopy);
    traj_main<<<Bsz / 64, 512, 0, stream>>>(fused, intent, Winit, binit, Wihl0, bihl0,
                                            bhhl0, bihl1, bhhl1, Wout, bout, pkw,
                                            ncopy - 1, (float*)d_out, Bsz);
}

// Round 5
// 3177.655 us; speedup vs baseline: 1.1664x; 1.1118x over previous
//
#include <hip/hip_runtime.h>

#define SEQ 12

typedef __attribute__((ext_vector_type(8))) short bf16x8;   // 8 bf16 bit patterns (4 VGPRs)
typedef __attribute__((ext_vector_type(4))) float f32x4;
typedef __attribute__((ext_vector_type(4))) unsigned short us4;

__device__ __forceinline__ unsigned short f2bf(float x) {
    unsigned u = __builtin_bit_cast(unsigned, x);
    u += 0x7fffu + ((u >> 16) & 1u);            // round-to-nearest-even
    return (unsigned short)(u >> 16);
}
__device__ __forceinline__ float bf2f(unsigned short h) {
    unsigned u = ((unsigned)h) << 16;
    return __builtin_bit_cast(float, u);
}
__device__ __forceinline__ float sigf(float x) { return 1.0f / (1.0f + __expf(-x)); }
__device__ __forceinline__ float tanhf_(float x) {
    x = fminf(fmaxf(x, -15.0f), 15.0f);
    float e = __expf(2.0f * x);
    return (e - 1.0f) / (e + 1.0f);
}

// ---------------- weight pack kernel ----------------
// d_ws layout (ushort), REPLICATED ncopy times at stride 327680 (640 KB/copy):
//   [0,131072)       L0F  = bf16([W_ih_l0[:,:128] | W_hh_l0])  fused K=256
//   [131072,262144)  L1   = bf16([W_ih_l1 | W_hh_l1])          fused K=256
//   [262144,327680)  INIT = bf16(W_init[:,:128])               K=128
// fragment order: chunk = ((w*4+G)*KK + kk), within chunk: lane*8+j,
//   n = G*128 + w*16 + (lane&15),  k = kk*32 + (lane>>4)*8 + j
__global__ void pack_w(const float* __restrict__ Winit, const float* __restrict__ Wihl0,
                       const float* __restrict__ Whhl0, const float* __restrict__ Wihl1,
                       const float* __restrict__ Whhl1, unsigned short* __restrict__ pk,
                       int ncopy) {
    int id = blockIdx.x * 256 + threadIdx.x;
    if (id >= 327680) return;
    float v;
    if (id < 131072) {                       // L0F, KK=8 (K=256)
        int c = id >> 9, r = id & 511;
        int lane = r >> 3, j = r & 7;
        int kk = c & 7, G = (c >> 3) & 3, w = c >> 5;
        int n = G * 128 + w * 16 + (lane & 15);
        int k = kk * 32 + (lane >> 4) * 8 + j;
        v = (k < 128) ? Wihl0[n * 129 + k] : Whhl0[n * 128 + (k - 128)];
    } else if (id < 262144) {                // L1, KK=8 (K=256)
        int e = id - 131072;
        int c = e >> 9, r = e & 511;
        int lane = r >> 3, j = r & 7;
        int kk = c & 7, G = (c >> 3) & 3, w = c >> 5;
        int n = G * 128 + w * 16 + (lane & 15);
        int k = kk * 32 + (lane >> 4) * 8 + j;
        v = (k < 128) ? Wihl1[n * 128 + k] : Whhl1[n * 128 + (k - 128)];
    } else {                                 // INIT, KK=4 (K=128)
        int e = id - 262144;
        int c = e >> 9, r = e & 511;
        int lane = r >> 3, j = r & 7;
        int kk = c & 3, G = (c >> 2) & 3, w = c >> 4;
        int n = G * 128 + w * 16 + (lane & 15);
        int k = kk * 32 + (lane >> 4) * 8 + j;
        v = Winit[n * 129 + k];
    }
    unsigned short hv = f2bf(v);
    for (int cpy = 0; cpy < ncopy; ++cpy) pk[cpy * 327680 + id] = hv;
}

// ---------------- fused decoder kernel ----------------
// block: 512 thr (8 waves), Mt=64 samples. wave w owns hidden cols [16w,16w+16)
// across all 4 gates -> LSTM pointwise is lane-local in MFMA C-layout.
// KEY (r5): no pre0 register state. x-tile stays in LDS; layer-0 is a fused
// K=256 GEMM [x|h1]@[Wihl0|Whhl0]^T re-executed each step (bit-identical math,
// +33% MFMA at 7% util) -> per-lane demand ~180 regs < 256 -> zero scratch spill.
// h1/h2 double-buffered (2 barriers/step). LDS ~103 KB, 1 block/CU.
__global__ __launch_bounds__(512) __attribute__((amdgpu_waves_per_eu(2, 2)))
void traj_main(const float* __restrict__ fused, const float* __restrict__ intent,
               const float* __restrict__ binit,
               const float* __restrict__ Winit, const float* __restrict__ Wihl0,
               const float* __restrict__ bihl0, const float* __restrict__ bhhl0,
               const float* __restrict__ bihl1, const float* __restrict__ bhhl1,
               const float* __restrict__ Wout, const float* __restrict__ bout,
               const unsigned short* __restrict__ pk, int copyMask,
               float* __restrict__ out, int Bsz) {
    __shared__ __align__(16) unsigned short s_x [64 * 128];      // x-tile, persistent
    __shared__ __align__(16) unsigned short s_xi[64 * 128];      // init-x tile (phase A)
    __shared__ __align__(16) unsigned short s_h1[2][64 * 128];   // h1 double buffer
    __shared__ __align__(16) unsigned short s_h2[2][64 * 128];   // h2 double buffer
    __shared__ float s_wo[256];                                  // W_out (2x128)
    __shared__ float s_out[64 * 24];                             // per-step outputs

    const int tid = threadIdx.x;
    const int lane = tid & 63;
    const int w = tid >> 6;          // wave 0..7
    const int nq = lane & 15;
    const int quad = lane >> 4;
    const int m0 = blockIdx.x * 64;
    const int Bh = Bsz >> 1;

    const unsigned short* pkb  = pk + (int)(blockIdx.x & copyMask) * 327680;
    const unsigned short* pkL0 = pkb;
    const unsigned short* pkL1 = pkb + 131072;
    const unsigned short* pkINI = pkb + 262144;

    if (tid < 256) s_wo[tid] = Wout[tid];
    const float bo = (tid < 128) ? bout[tid & 1] : 0.0f;

    // per-lane column constants (n = G*128 + 16w + nq)
    float bpre[4], bl1[4], wcp[4], wci[4], bini[4];
#pragma unroll
    for (int G = 0; G < 4; ++G) {
        int n = G * 128 + w * 16 + nq;
        bpre[G] = bihl0[n] + bhhl0[n];
        bl1[G]  = bihl1[n] + bhhl1[n];
        wcp[G]  = Wihl0[n * 129 + 128];    // intent column of W_ih_l0
        wci[G]  = Winit[n * 129 + 128];    // intent column of W_init
        bini[G] = binit[n];
    }
    // per-lane intent values for the 16 sample rows this lane owns in C-layout
    float ivr[4][4];
#pragma unroll
    for (int mt = 0; mt < 4; ++mt)
#pragma unroll
        for (int r = 0; r < 4; ++r) ivr[mt][r] = intent[m0 + mt * 16 + quad * 4 + r];

    // ---- stage tiles as bf16 (swizzled A-layout): rows 0..63 samples -> s_x,
    //      rows 64..95 init rows m0/2.., rows 96..127 init rows B/2+m0/2.. -> s_xi
#pragma unroll
    for (int it = 0; it < 8; ++it) {
        int f = it * 512 + tid;
        int row = f >> 5, fc = f & 31;
        int g = (row < 64) ? (m0 + row)
                           : ((row < 96) ? ((m0 >> 1) + (row - 64))
                                         : (Bh + (m0 >> 1) + (row - 96)));
        f32x4 v = *(const f32x4*)(fused + g * 128 + fc * 4);
        us4 u;
#pragma unroll
        for (int j = 0; j < 4; ++j) u[j] = f2bf(v[j]);
        int m = row & 63;
        int cp = (fc >> 1) ^ (m & 15);
        unsigned short* buf = (row < 64) ? s_x : s_xi;
        *(us4*)&buf[m * 128 + cp * 8 + (fc & 1) * 4] = u;
    }
    __syncthreads();

    // ---- phase A: initacc = x'@Winit^T (+b,+intent)  (K=128, 64 MFMA/wave)
    f32x4 acc2[4][4];
#pragma unroll
    for (int mt = 0; mt < 4; ++mt)
#pragma unroll
        for (int G = 0; G < 4; ++G) acc2[mt][G] = (f32x4){0.f, 0.f, 0.f, 0.f};
#pragma unroll
    for (int kk = 0; kk < 4; ++kk) {
        bf16x8 a2[4], b2[4];
#pragma unroll
        for (int mt = 0; mt < 4; ++mt)
            a2[mt] = *(const bf16x8*)&s_xi[(mt * 16 + nq) * 128 + (((kk * 4 + quad) ^ nq) << 3)];
#pragma unroll
        for (int G = 0; G < 4; ++G)
            b2[G] = *(const bf16x8*)&pkINI[((w * 4 + G) * 4 + kk) * 512 + lane * 8];
#pragma unroll
        for (int mt = 0; mt < 4; ++mt)
#pragma unroll
            for (int G = 0; G < 4; ++G)
                acc2[mt][G] = __builtin_amdgcn_mfma_f32_16x16x32_bf16(a2[mt], b2[G], acc2[mt][G], 0, 0, 0);
    }
#pragma unroll
    for (int mt = 0; mt < 4; ++mt)
#pragma unroll
        for (int r = 0; r < 4; ++r) {
            int ml = mt * 16 + quad * 4 + r;
            int grow = (mt < 2) ? ((m0 >> 1) + ml) : (Bh + (m0 >> 1) + (ml - 32));
            float iv2 = intent[grow];
#pragma unroll
            for (int G = 0; G < 4; ++G) acc2[mt][G][r] += bini[G] + iv2 * wci[G];
        }

    // ---- unpack init (torch-faithful flat reshape of [B,2H]->(2,B,H)):
    // init row r=(m>>1): G0->h even cols, G1->h odd, G2->c even, G3->c odd;
    // mt 0,1 -> layer0, mt 2,3 -> layer1. h -> s_h*[0] (swizzled),
    // c -> s_h*[1] (plain [ml*128+kq]) -- read into regs before step 0 overwrites.
    {
        int kq = w * 16 + nq, kc = kq >> 3, klo = kq & 7;
#pragma unroll
        for (int mt = 0; mt < 4; ++mt)
#pragma unroll
            for (int r = 0; r < 4; ++r) {
                int ri = mt * 16 + quad * 4 + r;
                int layer = mt >> 1;
                int ril = ri & 31;
#pragma unroll
                for (int G = 0; G < 4; ++G) {
                    int ml = 2 * ril + (G & 1);
                    unsigned short hv = f2bf(acc2[mt][G][r]);
                    if (G < 2) {
                        unsigned short* hb = layer ? s_h2[0] : s_h1[0];
                        hb[ml * 128 + ((kc ^ (ml & 15)) << 3) + klo] = hv;
                    } else {
                        unsigned short* cb = layer ? s_h2[1] : s_h1[1];
                        cb[ml * 128 + kq] = hv;
                    }
                }
            }
    }
    __syncthreads();

    // ---- load c into C-layout registers
    f32x4 c1v[4], c2v[4];
    {
        int kq = w * 16 + nq;
#pragma unroll
        for (int mt = 0; mt < 4; ++mt)
#pragma unroll
            for (int r = 0; r < 4; ++r) {
                int ml = mt * 16 + quad * 4 + r;
                c1v[mt][r] = bf2f(s_h1[1][ml * 128 + kq]);
                c2v[mt][r] = bf2f(s_h2[1][ml * 128 + kq]);
            }
    }
    __syncthreads();   // c reads done before step 0 overwrites s_h*[1]

    // ---- 12 decode steps, state resident (unroll 1: keep body I-cache sized)
#pragma unroll 1
    for (int s = 0; s < SEQ; ++s) {
        const int p = s & 1;
        const unsigned short* h1r = s_h1[p];
        unsigned short*       h1w = s_h1[1 - p];
        const unsigned short* h2r = s_h2[p];
        unsigned short*       h2w = s_h2[1 - p];

        f32x4 acc[4][4];
        // layer0: acc = bpre + iv*wcp; then fused [x | h1] @ [Wihl0 | Whhl0]^T
#pragma unroll
        for (int mt = 0; mt < 4; ++mt)
#pragma unroll
            for (int G = 0; G < 4; ++G)
#pragma unroll
                for (int r = 0; r < 4; ++r)
                    acc[mt][G][r] = bpre[G] + ivr[mt][r] * wcp[G];
#pragma unroll
        for (int kk = 0; kk < 8; ++kk) {
            const unsigned short* ab = (kk < 4) ? s_x : h1r;
            int kkl = kk & 3;
            bf16x8 a[4], b[4];
#pragma unroll
            for (int mt = 0; mt < 4; ++mt)
                a[mt] = *(const bf16x8*)&ab[(mt * 16 + nq) * 128 + (((kkl * 4 + quad) ^ nq) << 3)];
#pragma unroll
            for (int G = 0; G < 4; ++G)
                b[G] = *(const bf16x8*)&pkL0[((w * 4 + G) * 8 + kk) * 512 + lane * 8];
#pragma unroll
            for (int mt = 0; mt < 4; ++mt)
#pragma unroll
                for (int G = 0; G < 4; ++G)
                    acc[mt][G] = __builtin_amdgcn_mfma_f32_16x16x32_bf16(a[mt], b[G], acc[mt][G], 0, 0, 0);
        }
#pragma unroll
        for (int mt = 0; mt < 4; ++mt)
#pragma unroll
            for (int r = 0; r < 4; ++r) {
                float iv = acc[mt][0][r], fv = acc[mt][1][r], gv = acc[mt][2][r], ov = acc[mt][3][r];
                float c = c1v[mt][r];
                float cn = sigf(fv) * c + sigf(iv) * tanhf_(gv);
                float hn = sigf(ov) * tanhf_(cn);
                c1v[mt][r] = cn;
                int ml = mt * 16 + quad * 4 + r;
                h1w[ml * 128 + ((((w * 2) + (nq >> 3)) ^ (quad * 4 + r)) << 3) + (nq & 7)] = f2bf(hn);
            }
        __syncthreads();   // B1: new h1 visible
        // layer1: acc = bl1; fused [h1_new | h2] @ [Wihl1 | Whhl1]^T (K=256)
#pragma unroll
        for (int mt = 0; mt < 4; ++mt)
#pragma unroll
            for (int G = 0; G < 4; ++G)
                acc[mt][G] = (f32x4){bl1[G], bl1[G], bl1[G], bl1[G]};
#pragma unroll
        for (int kk = 0; kk < 8; ++kk) {
            const unsigned short* ab = (kk < 4) ? h1w : h2r;
            int kkl = kk & 3;
            bf16x8 a[4], b[4];
#pragma unroll
            for (int mt = 0; mt < 4; ++mt)
                a[mt] = *(const bf16x8*)&ab[(mt * 16 + nq) * 128 + (((kkl * 4 + quad) ^ nq) << 3)];
#pragma unroll
            for (int G = 0; G < 4; ++G)
                b[G] = *(const bf16x8*)&pkL1[((w * 4 + G) * 8 + kk) * 512 + lane * 8];
#pragma unroll
            for (int mt = 0; mt < 4; ++mt)
#pragma unroll
                for (int G = 0; G < 4; ++G)
                    acc[mt][G] = __builtin_amdgcn_mfma_f32_16x16x32_bf16(a[mt], b[G], acc[mt][G], 0, 0, 0);
        }
#pragma unroll
        for (int mt = 0; mt < 4; ++mt)
#pragma unroll
            for (int r = 0; r < 4; ++r) {
                float iv = acc[mt][0][r], fv = acc[mt][1][r], gv = acc[mt][2][r], ov = acc[mt][3][r];
                float c = c2v[mt][r];
                float cn = sigf(fv) * c + sigf(iv) * tanhf_(gv);
                float hn = sigf(ov) * tanhf_(cn);
                c2v[mt][r] = cn;
                int ml = mt * 16 + quad * 4 + r;
                h2w[ml * 128 + ((((w * 2) + (nq >> 3)) ^ (quad * 4 + r)) << 3) + (nq & 7)] = f2bf(hn);
            }
        __syncthreads();   // B2: new h2 visible
        // output head (fp32): out[m, s, :] = h2_new @ Wout^T + bout -> LDS staging
        if (tid < 128) {
            int ml = tid >> 1, oc = tid & 1;
            const float* wr = s_wo + oc * 128;
            float s0 = 0.f, s1 = 0.f;
            int mx = ml & 15;
#pragma unroll
            for (int c = 0; c < 16; ++c) {
                int base = ml * 128 + ((c ^ mx) << 3);
                int k0 = c << 3;
#pragma unroll
                for (int j = 0; j < 8; j += 2) {
                    unsigned u = *(const unsigned*)&h2w[base + j];
                    s0 += bf2f((unsigned short)u) * wr[k0 + j];
                    s1 += bf2f((unsigned short)(u >> 16)) * wr[k0 + j + 1];
                }
            }
            s_out[ml * 24 + s * 2 + oc] = s0 + s1 + bo;
        }
    }
    __syncthreads();
    // single contiguous coalesced store: 64 samples x 24 floats = 6 KB
    for (int i = tid; i < 1536; i += 512) out[m0 * 24 + i] = s_out[i];
}

extern "C" void kernel_launch(void* const* d_in, const int* in_sizes, int n_in,
                              void* d_out, int out_size, void* d_ws, size_t ws_size,
                              hipStream_t stream) {
    const float* fused  = (const float*)d_in[0];
    const float* intent = (const float*)d_in[1];
    const float* Winit  = (const float*)d_in[2];
    const float* binit  = (const float*)d_in[3];
    const float* Wihl0  = (const float*)d_in[4];
    const float* Whhl0  = (const float*)d_in[5];
    const float* bihl0  = (const float*)d_in[6];
    const float* bhhl0  = (const float*)d_in[7];
    const float* Wihl1  = (const float*)d_in[8];
    const float* Whhl1  = (const float*)d_in[9];
    const float* bihl1  = (const float*)d_in[10];
    const float* bhhl1  = (const float*)d_in[11];
    const float* Wout   = (const float*)d_in[12];
    const float* bout   = (const float*)d_in[13];
    int Bsz = in_sizes[0] / 128;

    // replicate packed weights: 1 copy per XCD (pow2 <= 8, limited by ws_size)
    int ncopy = 1;
    while (ncopy < 8 && (size_t)(ncopy * 2) * 655360ull <= ws_size) ncopy <<= 1;

    unsigned short* pkw = (unsigned short*)d_ws;   // ncopy * 640 KB used
    pack_w<<<1280, 256, 0, stream>>>(Winit, Wihl0, Whhl0, Wihl1, Whhl1, pkw, ncopy);
    traj_main<<<Bsz / 64, 512, 0, stream>>>(fused, intent, binit, Winit, Wihl0, bihl0,
                                            bhhl0, bihl1, bhhl1, Wout, bout, pkw,
                                            ncopy - 1, (float*)d_out, Bsz);
}

// Round 6
// 2678.544 us; speedup vs baseline: 1.3837x; 1.1863x over previous
//
#include <hip/hip_runtime.h>

#define SEQ 12

typedef __attribute__((ext_vector_type(8))) short bf16x8;   // 8 bf16 bit patterns (4 VGPRs)
typedef __attribute__((ext_vector_type(4))) float f32x4;
typedef __attribute__((ext_vector_type(4))) unsigned short us4;

__device__ __forceinline__ unsigned short f2bf(float x) {
    unsigned u = __builtin_bit_cast(unsigned, x);
    u += 0x7fffu + ((u >> 16) & 1u);            // round-to-nearest-even
    return (unsigned short)(u >> 16);
}
__device__ __forceinline__ float bf2f(unsigned short h) {
    unsigned u = ((unsigned)h) << 16;
    return __builtin_bit_cast(float, u);
}
__device__ __forceinline__ float sigf(float x) { return 1.0f / (1.0f + __expf(-x)); }
__device__ __forceinline__ float tanhf_(float x) {
    x = fminf(fmaxf(x, -15.0f), 15.0f);
    float e = __expf(2.0f * x);
    return (e - 1.0f) / (e + 1.0f);
}

// ---------------- weight pack kernel ----------------
// d_ws layout (ushort), REPLICATED ncopy times at stride 327680 (640 KB/copy):
//   [0,65536)        PRE0 = bf16(W_ih_l0[:, :128])  K=128
//   [65536,131072)   INIT = bf16(W_init [:, :128])  K=128
//   [131072,196608)  L0   = bf16(W_hh_l0)           K=128
//   [196608,327680)  L1   = bf16([W_ih_l1|W_hh_l1]) K=256
// fragment order: chunk = ((w*4+G)*KK + kk), within chunk: lane*8+j,
//   n = G*128 + w*16 + (lane&15),  k = kk*32 + (lane>>4)*8 + j
__global__ void pack_w(const float* __restrict__ Winit, const float* __restrict__ Wihl0,
                       const float* __restrict__ Whhl0, const float* __restrict__ Wihl1,
                       const float* __restrict__ Whhl1, unsigned short* __restrict__ pk,
                       int ncopy) {
    int id = blockIdx.x * 256 + threadIdx.x;
    if (id >= 327680) return;
    float v;
    if (id < 131072) {                       // PRE0 / INIT (stride 129, KK=4)
        int e = id & 65535;
        int c = e >> 9, r = e & 511;
        int lane = r >> 3, j = r & 7;
        int kk = c & 3, G = (c >> 2) & 3, w = c >> 4;
        int n = G * 128 + w * 16 + (lane & 15);
        int k = kk * 32 + (lane >> 4) * 8 + j;
        const float* W = (id >> 16) ? Winit : Wihl0;
        v = W[n * 129 + k];
    } else if (id < 196608) {                // L0 (stride 128, KK=4)
        int e = id - 131072;
        int c = e >> 9, r = e & 511;
        int lane = r >> 3, j = r & 7;
        int kk = c & 3, G = (c >> 2) & 3, w = c >> 4;
        int n = G * 128 + w * 16 + (lane & 15);
        int k = kk * 32 + (lane >> 4) * 8 + j;
        v = Whhl0[n * 128 + k];
    } else {                                 // L1 (K=256, KK=8)
        int e = id - 196608;
        int c = e >> 9, r = e & 511;
        int lane = r >> 3, j = r & 7;
        int kk = c & 7, G = (c >> 3) & 3, w = c >> 5;
        int n = G * 128 + w * 16 + (lane & 15);
        int k = kk * 32 + (lane >> 4) * 8 + j;
        v = (k < 128) ? Wihl1[n * 128 + k] : Whhl1[n * 128 + (k - 128)];
    }
    unsigned short hv = f2bf(v);
    for (int cpy = 0; cpy < ncopy; ++cpy) pk[cpy * 327680 + id] = hv;
}

// per-group helpers (macros so everything stays in registers, fully unrolled)
#define LOAD_A(hb, kkl) do { _Pragma("unroll") \
    for (int mt = 0; mt < 4; ++mt) \
        a[mt] = *(const bf16x8*)&(hb)[(mt * 16 + nq) * 128 + ((((kkl) * 4 + quad) ^ nq) << 3)]; \
    } while (0)
#define LOAD_B(slot, base, KK, kk) do { _Pragma("unroll") \
    for (int G = 0; G < 4; ++G) \
        bb[slot][G] = *(const bf16x8*)&(base)[((w * 4 + G) * (KK) + (kk)) * 512 + lane * 8]; \
    } while (0)
#define MFMA_G(slot) do { _Pragma("unroll") \
    for (int mt = 0; mt < 4; ++mt) { _Pragma("unroll") \
        for (int G = 0; G < 4; ++G) \
            acc[mt][G] = __builtin_amdgcn_mfma_f32_16x16x32_bf16(a[mt], bb[slot][G], acc[mt][G], 0, 0, 0); } \
    } while (0)

// ---------------- fused decoder kernel ----------------
// block: 512 thr (8 waves), Mt=64. wave w owns hidden cols [16w,16w+16) x 4 gates.
// r6: pre0 back in AGPR (K=128 layer0, -25% weight traffic) + software-
// prefetched weight ring: the 12 B-fragment groups per step are loaded 2+
// groups ahead (ping-pong bb[2][4]), with refills issued before the pointwise/
// barrier gaps -> VMEM latency overlapped instead of serialized per group.
__global__ __launch_bounds__(512) __attribute__((amdgpu_waves_per_eu(2, 2)))
void traj_main(const float* __restrict__ fused, const float* __restrict__ intent,
               const float* __restrict__ binit,
               const float* __restrict__ Winit, const float* __restrict__ Wihl0,
               const float* __restrict__ bihl0, const float* __restrict__ bhhl0,
               const float* __restrict__ bihl1, const float* __restrict__ bhhl1,
               const float* __restrict__ Wout, const float* __restrict__ bout,
               const unsigned short* __restrict__ pk, int copyMask,
               float* __restrict__ out, int Bsz) {
    __shared__ __align__(16) unsigned short s_x [64 * 128];      // x-tile (phase A only)
    __shared__ __align__(16) unsigned short s_xi[64 * 128];      // init-x tile (phase A only)
    __shared__ __align__(16) unsigned short s_h1[2][64 * 128];   // h1 double buffer ([1] = c1 staging pre-loop)
    __shared__ __align__(16) unsigned short s_h2[2][64 * 128];   // h2 double buffer ([1] = c2 staging pre-loop)
    __shared__ float s_wo[256];                                  // W_out (2x128)
    __shared__ float s_out[64 * 24];                             // per-step outputs

    const int tid = threadIdx.x;
    const int lane = tid & 63;
    const int w = tid >> 6;          // wave 0..7
    const int nq = lane & 15;
    const int quad = lane >> 4;
    const int m0 = blockIdx.x * 64;
    const int Bh = Bsz >> 1;

    const unsigned short* pkb   = pk + (int)(blockIdx.x & copyMask) * 327680;
    const unsigned short* pkPRE = pkb;
    const unsigned short* pkINI = pkb + 65536;
    const unsigned short* pkL0  = pkb + 131072;
    const unsigned short* pkL1  = pkb + 196608;

    if (tid < 256) s_wo[tid] = Wout[tid];
    const float bo = (tid < 128) ? bout[tid & 1] : 0.0f;

    // per-lane column constants (n = G*128 + 16w + nq)
    float bpre[4], bl1[4], wcp[4], wci[4], bini[4];
#pragma unroll
    for (int G = 0; G < 4; ++G) {
        int n = G * 128 + w * 16 + nq;
        bpre[G] = bihl0[n] + bhhl0[n];
        bl1[G]  = bihl1[n] + bhhl1[n];
        wcp[G]  = Wihl0[n * 129 + 128];    // intent column of W_ih_l0
        wci[G]  = Winit[n * 129 + 128];    // intent column of W_init
        bini[G] = binit[n];
    }

    // ---- stage tiles as bf16 (swizzled A-layout)
#pragma unroll
    for (int it = 0; it < 8; ++it) {
        int f = it * 512 + tid;
        int row = f >> 5, fc = f & 31;
        int g = (row < 64) ? (m0 + row)
                           : ((row < 96) ? ((m0 >> 1) + (row - 64))
                                         : (Bh + (m0 >> 1) + (row - 96)));
        f32x4 v = *(const f32x4*)(fused + g * 128 + fc * 4);
        us4 u;
#pragma unroll
        for (int j = 0; j < 4; ++j) u[j] = f2bf(v[j]);
        int m = row & 63;
        int cp = (fc >> 1) ^ (m & 15);
        unsigned short* buf = (row < 64) ? s_x : s_xi;
        *(us4*)&buf[m * 128 + cp * 8 + (fc & 1) * 4] = u;
    }
    __syncthreads();

    // ---- phase A: pre0 = x@Wihl0^T (+b,+intent), initacc = x'@Winit^T (+b,+intent)
    f32x4 pre0[4][4], acc2[4][4];
#pragma unroll
    for (int mt = 0; mt < 4; ++mt)
#pragma unroll
        for (int G = 0; G < 4; ++G) {
            pre0[mt][G] = (f32x4){0.f, 0.f, 0.f, 0.f};
            acc2[mt][G] = (f32x4){0.f, 0.f, 0.f, 0.f};
        }
#pragma unroll
    for (int kk = 0; kk < 4; ++kk) {
        bf16x8 av[4], bv[4], a2[4], b2[4];
#pragma unroll
        for (int mt = 0; mt < 4; ++mt) {
            int idx = (mt * 16 + nq) * 128 + (((kk * 4 + quad) ^ nq) << 3);
            av[mt] = *(const bf16x8*)&s_x[idx];
            a2[mt] = *(const bf16x8*)&s_xi[idx];
        }
#pragma unroll
        for (int G = 0; G < 4; ++G) {
            int off = ((w * 4 + G) * 4 + kk) * 512 + lane * 8;
            bv[G] = *(const bf16x8*)&pkPRE[off];
            b2[G] = *(const bf16x8*)&pkINI[off];
        }
#pragma unroll
        for (int mt = 0; mt < 4; ++mt)
#pragma unroll
            for (int G = 0; G < 4; ++G) {
                pre0[mt][G] = __builtin_amdgcn_mfma_f32_16x16x32_bf16(av[mt], bv[G], pre0[mt][G], 0, 0, 0);
                acc2[mt][G] = __builtin_amdgcn_mfma_f32_16x16x32_bf16(a2[mt], b2[G], acc2[mt][G], 0, 0, 0);
            }
    }
#pragma unroll
    for (int mt = 0; mt < 4; ++mt)
#pragma unroll
        for (int r = 0; r < 4; ++r) {
            int ml = mt * 16 + quad * 4 + r;
            float iv = intent[m0 + ml];
            int grow = (mt < 2) ? ((m0 >> 1) + ml) : (Bh + (m0 >> 1) + (ml - 32));
            float iv2 = intent[grow];
#pragma unroll
            for (int G = 0; G < 4; ++G) {
                pre0[mt][G][r] += bpre[G] + iv * wcp[G];
                acc2[mt][G][r] += bini[G] + iv2 * wci[G];
            }
        }
    __syncthreads();   // x-tile reads complete

    // ---- unpack init (torch-faithful flat reshape of [B,2H]->(2,B,H)):
    // init row r=(m>>1): G0->h even cols, G1->h odd, G2->c even, G3->c odd;
    // mt 0,1 -> layer0, mt 2,3 -> layer1. h -> s_h*[0] (swizzled), c -> s_h*[1].
    {
        int kq = w * 16 + nq, kc = kq >> 3, klo = kq & 7;
#pragma unroll
        for (int mt = 0; mt < 4; ++mt)
#pragma unroll
            for (int r = 0; r < 4; ++r) {
                int ri = mt * 16 + quad * 4 + r;
                int layer = mt >> 1;
                int ril = ri & 31;
#pragma unroll
                for (int G = 0; G < 4; ++G) {
                    int ml = 2 * ril + (G & 1);
                    unsigned short hv = f2bf(acc2[mt][G][r]);
                    if (G < 2) {
                        unsigned short* hb = layer ? s_h2[0] : s_h1[0];
                        hb[ml * 128 + ((kc ^ (ml & 15)) << 3) + klo] = hv;
                    } else {
                        unsigned short* cb = layer ? s_h2[1] : s_h1[1];
                        cb[ml * 128 + kq] = hv;
                    }
                }
            }
    }
    __syncthreads();

    // ---- load c into C-layout registers
    f32x4 c1v[4], c2v[4];
    {
        int kq = w * 16 + nq;
#pragma unroll
        for (int mt = 0; mt < 4; ++mt)
#pragma unroll
            for (int r = 0; r < 4; ++r) {
                int ml = mt * 16 + quad * 4 + r;
                c1v[mt][r] = bf2f(s_h1[1][ml * 128 + kq]);
                c2v[mt][r] = bf2f(s_h2[1][ml * 128 + kq]);
            }
    }
    __syncthreads();   // c reads done before step 0 overwrites s_h*[1]

    // ---- prefetch ring warm-up: first two weight groups of step 0
    bf16x8 bb[2][4];
    LOAD_B(0, pkL0, 4, 0);
    LOAD_B(1, pkL0, 4, 1);

    // ---- 12 decode steps; ring of 12 groups/step: L0 k0..3, L1 k0..7.
    // pattern per group: MFMA(slot) then refill same slot with group 2 ahead.
#pragma unroll 1
    for (int s = 0; s < SEQ; ++s) {
        const int p = s & 1;
        const unsigned short* h1r = s_h1[p];
        unsigned short*       h1w = s_h1[1 - p];
        const unsigned short* h2r = s_h2[p];
        unsigned short*       h2w = s_h2[1 - p];

        f32x4 acc[4][4];
        bf16x8 a[4];
        // layer0: acc = pre0 + h1 @ Whhl0^T  (K=128)
#pragma unroll
        for (int mt = 0; mt < 4; ++mt)
#pragma unroll
            for (int G = 0; G < 4; ++G) acc[mt][G] = pre0[mt][G];
        LOAD_A(h1r, 0); MFMA_G(0); LOAD_B(0, pkL0, 4, 2);
        LOAD_A(h1r, 1); MFMA_G(1); LOAD_B(1, pkL0, 4, 3);
        LOAD_A(h1r, 2); MFMA_G(0); LOAD_B(0, pkL1, 8, 0);
        LOAD_A(h1r, 3); MFMA_G(1); LOAD_B(1, pkL1, 8, 1);
        // pointwise layer0 (loads for L1 k0/k1 in flight, covered by this + barrier)
#pragma unroll
        for (int mt = 0; mt < 4; ++mt)
#pragma unroll
            for (int r = 0; r < 4; ++r) {
                float iv = acc[mt][0][r], fv = acc[mt][1][r], gv = acc[mt][2][r], ov = acc[mt][3][r];
                float c = c1v[mt][r];
                float cn = sigf(fv) * c + sigf(iv) * tanhf_(gv);
                float hn = sigf(ov) * tanhf_(cn);
                c1v[mt][r] = cn;
                int ml = mt * 16 + quad * 4 + r;
                h1w[ml * 128 + ((((w * 2) + (nq >> 3)) ^ (quad * 4 + r)) << 3) + (nq & 7)] = f2bf(hn);
            }
        __syncthreads();   // B1: new h1 visible
        // layer1: acc = bl1 + [h1_new | h2] @ [Wihl1 | Whhl1]^T  (K=256)
#pragma unroll
        for (int mt = 0; mt < 4; ++mt)
#pragma unroll
            for (int G = 0; G < 4; ++G)
                acc[mt][G] = (f32x4){bl1[G], bl1[G], bl1[G], bl1[G]};
        LOAD_A(h1w, 0); MFMA_G(0); LOAD_B(0, pkL1, 8, 2);
        LOAD_A(h1w, 1); MFMA_G(1); LOAD_B(1, pkL1, 8, 3);
        LOAD_A(h1w, 2); MFMA_G(0); LOAD_B(0, pkL1, 8, 4);
        LOAD_A(h1w, 3); MFMA_G(1); LOAD_B(1, pkL1, 8, 5);
        LOAD_A(h2r, 0); MFMA_G(0); LOAD_B(0, pkL1, 8, 6);
        LOAD_A(h2r, 1); MFMA_G(1); LOAD_B(1, pkL1, 8, 7);
        LOAD_A(h2r, 2); MFMA_G(0); LOAD_B(0, pkL0, 4, 0);   // next step L0 k0
        LOAD_A(h2r, 3); MFMA_G(1); LOAD_B(1, pkL0, 4, 1);   // next step L0 k1
        // pointwise layer1 (next-step L0 loads in flight over pointwise+head+barrier)
#pragma unroll
        for (int mt = 0; mt < 4; ++mt)
#pragma unroll
            for (int r = 0; r < 4; ++r) {
                float iv = acc[mt][0][r], fv = acc[mt][1][r], gv = acc[mt][2][r], ov = acc[mt][3][r];
                float c = c2v[mt][r];
                float cn = sigf(fv) * c + sigf(iv) * tanhf_(gv);
                float hn = sigf(ov) * tanhf_(cn);
                c2v[mt][r] = cn;
                int ml = mt * 16 + quad * 4 + r;
                h2w[ml * 128 + ((((w * 2) + (nq >> 3)) ^ (quad * 4 + r)) << 3) + (nq & 7)] = f2bf(hn);
            }
        __syncthreads();   // B2: new h2 visible
        // output head (fp32): out[m, s, :] = h2_new @ Wout^T + bout -> LDS staging
        if (tid < 128) {
            int ml = tid >> 1, oc = tid & 1;
            const float* wr = s_wo + oc * 128;
            float s0 = 0.f, s1 = 0.f;
            int mx = ml & 15;
#pragma unroll
            for (int c = 0; c < 16; ++c) {
                int base = ml * 128 + ((c ^ mx) << 3);
                int k0 = c << 3;
#pragma unroll
                for (int j = 0; j < 8; j += 2) {
                    unsigned u = *(const unsigned*)&h2w[base + j];
                    s0 += bf2f((unsigned short)u) * wr[k0 + j];
                    s1 += bf2f((unsigned short)(u >> 16)) * wr[k0 + j + 1];
                }
            }
            s_out[ml * 24 + s * 2 + oc] = s0 + s1 + bo;
        }
    }
    __syncthreads();
    // single contiguous coalesced store: 64 samples x 24 floats = 6 KB
    for (int i = tid; i < 1536; i += 512) out[m0 * 24 + i] = s_out[i];
}

extern "C" void kernel_launch(void* const* d_in, const int* in_sizes, int n_in,
                              void* d_out, int out_size, void* d_ws, size_t ws_size,
                              hipStream_t stream) {
    const float* fused  = (const float*)d_in[0];
    const float* intent = (const float*)d_in[1];
    const float* Winit  = (const float*)d_in[2];
    const float* binit  = (const float*)d_in[3];
    const float* Wihl0  = (const float*)d_in[4];
    const float* Whhl0  = (const float*)d_in[5];
    const float* bihl0  = (const float*)d_in[6];
    const float* bhhl0  = (const float*)d_in[7];
    const float* Wihl1  = (const float*)d_in[8];
    const float* Whhl1  = (const float*)d_in[9];
    const float* bihl1  = (const float*)d_in[10];
    const float* bhhl1  = (const float*)d_in[11];
    const float* Wout   = (const float*)d_in[12];
    const float* bout   = (const float*)d_in[13];
    int Bsz = in_sizes[0] / 128;

    // replicate packed weights: 1 copy per XCD (pow2 <= 8, limited by ws_size)
    int ncopy = 1;
    while (ncopy < 8 && (size_t)(ncopy * 2) * 655360ull <= ws_size) ncopy <<= 1;

    unsigned short* pkw = (unsigned short*)d_ws;   // ncopy * 640 KB used
    pack_w<<<1280, 256, 0, stream>>>(Winit, Wihl0, Whhl0, Wihl1, Whhl1, pkw, ncopy);
    traj_main<<<Bsz / 64, 512, 0, stream>>>(fused, intent, binit, Winit, Wihl0, bihl0,
                                            bhhl0, bihl1, bhhl1, Wout, bout, pkw,
                                            ncopy - 1, (float*)d_out, Bsz);
}